// Round 15
// baseline (137.623 us; speedup 1.0000x reference)
//
#include <hip/hip_runtime.h>
#include <stdint.h>

#define LSEQ 512
#define HDIM 2048
#define NH 64
#define HD 64
#define INTER 4096
#define NG 4
#define NSTATE 64
#define CONVC 4608
#define PROJC 8768
#define EPS 1e-5f
#define CL 64
#define NC 8
#define NHDN (NH * HD * NSTATE)

typedef __attribute__((ext_vector_type(8))) short bf16x8;
typedef __attribute__((ext_vector_type(4))) short short4v;
typedef __attribute__((ext_vector_type(4))) float f32x4;

__device__ __forceinline__ short f2bf(float f) {
  union { float f; uint32_t u; } v; v.f = f;
  uint32_t r = v.u + 0x7FFFu + ((v.u >> 16) & 1u);
  return (short)(r >> 16);
}

__device__ __forceinline__ float bf2f(short s) {
  union { uint32_t u; float f; } v; v.u = ((uint32_t)(uint16_t)s) << 16;
  return v.f;
}

__device__ __forceinline__ float siluf(float v) {
  return v / (1.f + expf(-v));
}

// bijective XCD-chunked swizzle (m204)
__device__ __forceinline__ int xcd_swizzle(int orig, int nwg) {
  int q = nwg >> 3, r = nwg & 7;
  int xcd = orig & 7, idx = orig >> 3;
  return (xcd < r ? xcd * (q + 1) : r * (q + 1) + (xcd - r) * q) + idx;
}

// ---------------- K1: x = h + r ; residual out ; hs = rmsnorm(x)*w -> bf16
__global__ __launch_bounds__(256) void k_add_rmsnorm(
    const float* __restrict__ hid, const float* __restrict__ res,
    const float* __restrict__ w, float* __restrict__ resid_out,
    short* __restrict__ hsb) {
  __shared__ float sred[4];
  const int row = blockIdx.x, tid = threadIdx.x;
  const float4* h4 = (const float4*)(hid + (size_t)row * HDIM);
  const float4* r4 = (const float4*)(res + (size_t)row * HDIM);
  float4* ro4 = (float4*)(resid_out + (size_t)row * HDIM);
  float4 a0 = h4[tid], b0 = r4[tid];
  float4 a1 = h4[tid + 256], b1 = r4[tid + 256];
  float4 xa, xb;
  xa.x = a0.x + b0.x; xa.y = a0.y + b0.y; xa.z = a0.z + b0.z; xa.w = a0.w + b0.w;
  xb.x = a1.x + b1.x; xb.y = a1.y + b1.y; xb.z = a1.z + b1.z; xb.w = a1.w + b1.w;
  ro4[tid] = xa; ro4[tid + 256] = xb;
  float ss = xa.x*xa.x + xa.y*xa.y + xa.z*xa.z + xa.w*xa.w
           + xb.x*xb.x + xb.y*xb.y + xb.z*xb.z + xb.w*xb.w;
  #pragma unroll
  for (int off = 32; off >= 1; off >>= 1) ss += __shfl_down(ss, off);
  if ((tid & 63) == 0) sred[tid >> 6] = ss;
  __syncthreads();
  float tot = sred[0] + sred[1] + sred[2] + sred[3];
  float rs = rsqrtf(tot / (float)HDIM + EPS);
  int e0 = tid * 4, e1 = (tid + 256) * 4;
  short4v s0, s1;
  s0.x = f2bf(xa.x * rs * w[e0+0]); s0.y = f2bf(xa.y * rs * w[e0+1]);
  s0.z = f2bf(xa.z * rs * w[e0+2]); s0.w = f2bf(xa.w * rs * w[e0+3]);
  s1.x = f2bf(xb.x * rs * w[e1+0]); s1.y = f2bf(xb.y * rs * w[e1+1]);
  s1.z = f2bf(xb.z * rs * w[e1+2]); s1.w = f2bf(xb.w * rs * w[e1+3]);
  *(short4v*)(hsb + (size_t)row * HDIM + e0) = s0;
  *(short4v*)(hsb + (size_t)row * HDIM + e1) = s1;
}

// ---------------- K2: dst[c][r] = bf16(src[r][c])   src: R x C f32
__global__ __launch_bounds__(256) void k_transpose_cvt(
    const float* __restrict__ src, short* __restrict__ dst, int R, int C) {
  __shared__ float tile[32][33];
  const int tx = threadIdx.x & 31, ty = threadIdx.x >> 5;
  const int c0 = blockIdx.x * 32, r0 = blockIdx.y * 32;
  #pragma unroll
  for (int i = 0; i < 4; ++i)
    tile[ty + i*8][tx] = src[(size_t)(r0 + ty + i*8) * C + c0 + tx];
  __syncthreads();
  #pragma unroll
  for (int i = 0; i < 4; ++i)
    dst[(size_t)(c0 + ty + i*8) * R + r0 + tx] = f2bf(tile[tx][ty + i*8]);
}

// ---------------- GEMM1t: proj = hs(bf16) * w1t(bf16, N x K)^T
// 2-buffer gload_lds staging, counted vmcnt. Epilogue routes into
// zbf (bf16) / xbc (bf16) / dtf (f32) by n-block. BM=128.
__global__ __launch_bounds__(256) void k_gemm1t(
    const short* __restrict__ A, const short* __restrict__ B,
    short* __restrict__ zbf, short* __restrict__ xbc,
    float* __restrict__ dtf) {
  constexpr int BM = 128, MR = 4, WROWS = 64;
  const int M = LSEQ, N = PROJC, K = HDIM;
  __shared__ short lA[2][BM * 64];
  __shared__ short lB[2][64 * 64];
  const int tid = threadIdx.x, lane = tid & 63, wid = tid >> 6;

  const int NMB = M / BM, NNB = N / 64;
  const int nwg = NMB * NNB;
  int wg = xcd_swizzle(blockIdx.x, nwg);
  const int mi = wg % NMB;
  const int ni = wg / NMB;
  const int m0 = mi * BM, n0 = ni * 64;
  const int wm = wid >> 1, wn = wid & 1;

  const int lrow8 = lane >> 3;
  const int cswz = ((lane & 7) ^ lrow8) * 8;

  auto stage = [&](int buf, int kt) {
    #pragma unroll
    for (int r2 = 0; r2 < MR; ++r2) {
      int idx = r2 * 4 + wid;
      __builtin_amdgcn_global_load_lds(
          (const __attribute__((address_space(1))) int*)(A + (size_t)(m0 + idx * 8 + lrow8) * K + kt + cswz),
          (__attribute__((address_space(3))) int*)(&lA[buf][idx * 512]),
          16, 0, 0);
    }
    #pragma unroll
    for (int r2 = 0; r2 < 2; ++r2) {
      int idx = r2 * 4 + wid;
      __builtin_amdgcn_global_load_lds(
          (const __attribute__((address_space(1))) int*)(B + (size_t)(n0 + idx * 8 + lrow8) * K + kt + cswz),
          (__attribute__((address_space(3))) int*)(&lB[buf][idx * 512]),
          16, 0, 0);
    }
  };

  f32x4 acc[MR][2] = {};
  const int lrow = lane & 15, lkb = (lane >> 4) * 8;
  const int NT = K >> 6;
  stage(0, 0);
  for (int t = 0; t < NT; ++t) {
    int cur = t & 1;
    if (t + 1 < NT) {
      stage(cur ^ 1, (t + 1) * 64);
      asm volatile("s_waitcnt vmcnt(6)" ::: "memory");
    } else {
      asm volatile("s_waitcnt vmcnt(0)" ::: "memory");
    }
    __builtin_amdgcn_s_barrier();
    #pragma unroll
    for (int kk = 0; kk < 2; ++kk) {
      bf16x8 a[MR], b[2];
      #pragma unroll
      for (int m = 0; m < MR; ++m) {
        int row = wm * WROWS + m * 16 + lrow;
        int colel = (kk * 32 + lkb) ^ ((row & 7) << 3);
        a[m] = *(const bf16x8*)&lA[cur][row * 64 + colel];
      }
      #pragma unroll
      for (int n = 0; n < 2; ++n) {
        int row = wn * 32 + n * 16 + lrow;
        int colel = (kk * 32 + lkb) ^ ((row & 7) << 3);
        b[n] = *(const bf16x8*)&lB[cur][row * 64 + colel];
      }
      #pragma unroll
      for (int m = 0; m < MR; ++m)
        #pragma unroll
        for (int n = 0; n < 2; ++n)
          acc[m][n] = __builtin_amdgcn_mfma_f32_16x16x32_bf16(a[m], b[n], acc[m][n], 0, 0, 0);
    }
    __builtin_amdgcn_s_barrier();
  }
  // epilogue: route by n-block (uniform branch)
  #pragma unroll
  for (int m = 0; m < MR; ++m) {
    int row = m0 + wm * WROWS + m * 16 + (lane >> 4) * 4;
    #pragma unroll
    for (int n = 0; n < 2; ++n) {
      int coll = wn * 32 + n * 16 + (lane & 15);
      #pragma unroll
      for (int r = 0; r < 4; ++r) {
        float v = acc[m][n][r];
        if (ni < 64)
          zbf[(size_t)(row + r) * INTER + n0 + coll] = f2bf(v);
        else if (ni < 136)
          xbc[(size_t)(row + r) * CONVC + (n0 - INTER) + coll] = f2bf(v);
        else
          dtf[(row + r) * 64 + coll] = v;
      }
    }
  }
}

// ---------------- GEMM-bf16 (gemm2): C = A(bf16) * B(bf16, N x K)^T
template <int BM, int KS>
__global__ __launch_bounds__(256) void k_gemm_bf16(
    const short* __restrict__ A, const short* __restrict__ B,
    float* __restrict__ C, int M, int N, int K) {
  __shared__ short lA[2][BM * 64];
  __shared__ short lB[2][64 * 64];
  const int tid = threadIdx.x;
  const int lane = tid & 63, wid = tid >> 6;
  constexpr int MR = BM / 32;
  constexpr int WROWS = BM / 2;

  const int NMB = M / BM, NNB = N / 64;
  const int nwg = NMB * NNB * KS;
  int wg = xcd_swizzle(blockIdx.x, nwg);
  const int mi = wg % NMB;
  int rest = wg / NMB;
  const int zi = (KS > 1) ? (rest % KS) : 0;
  const int ni = (KS > 1) ? (rest / KS) : rest;
  const int m0 = mi * BM, n0 = ni * 64;
  const int wm = wid >> 1, wn = wid & 1;

  const int lrow8 = lane >> 3;
  const int cswz = ((lane & 7) ^ lrow8) * 8;

  const int Kc = K / KS;
  const int kbase = zi * Kc;
  float* Cp = C + (size_t)zi * M * N;

  auto stage = [&](int buf, int kt) {
    #pragma unroll
    for (int r2 = 0; r2 < MR; ++r2) {
      int idx = r2 * 4 + wid;
      __builtin_amdgcn_global_load_lds(
          (const __attribute__((address_space(1))) int*)(A + (size_t)(m0 + idx * 8 + lrow8) * K + kt + cswz),
          (__attribute__((address_space(3))) int*)(&lA[buf][idx * 512]),
          16, 0, 0);
    }
    #pragma unroll
    for (int r2 = 0; r2 < 2; ++r2) {
      int idx = r2 * 4 + wid;
      __builtin_amdgcn_global_load_lds(
          (const __attribute__((address_space(1))) int*)(B + (size_t)(n0 + idx * 8 + lrow8) * K + kt + cswz),
          (__attribute__((address_space(3))) int*)(&lB[buf][idx * 512]),
          16, 0, 0);
    }
  };

  f32x4 acc[MR][2] = {};
  const int lrow = lane & 15, lkb = (lane >> 4) * 8;
  const int NT = Kc >> 6;
  stage(0, kbase);
  for (int t = 0; t < NT; ++t) {
    int cur = t & 1;
    if (t + 1 < NT) {
      stage(cur ^ 1, kbase + (t + 1) * 64);
      if constexpr (MR == 2) asm volatile("s_waitcnt vmcnt(4)" ::: "memory");
      else                   asm volatile("s_waitcnt vmcnt(6)" ::: "memory");
    } else {
      asm volatile("s_waitcnt vmcnt(0)" ::: "memory");
    }
    __builtin_amdgcn_s_barrier();
    #pragma unroll
    for (int kk = 0; kk < 2; ++kk) {
      bf16x8 a[MR], b[2];
      #pragma unroll
      for (int m = 0; m < MR; ++m) {
        int row = wm * WROWS + m * 16 + lrow;
        int colel = (kk * 32 + lkb) ^ ((row & 7) << 3);
        a[m] = *(const bf16x8*)&lA[cur][row * 64 + colel];
      }
      #pragma unroll
      for (int n = 0; n < 2; ++n) {
        int row = wn * 32 + n * 16 + lrow;
        int colel = (kk * 32 + lkb) ^ ((row & 7) << 3);
        b[n] = *(const bf16x8*)&lB[cur][row * 64 + colel];
      }
      #pragma unroll
      for (int m = 0; m < MR; ++m)
        #pragma unroll
        for (int n = 0; n < 2; ++n)
          acc[m][n] = __builtin_amdgcn_mfma_f32_16x16x32_bf16(a[m], b[n], acc[m][n], 0, 0, 0);
    }
    __builtin_amdgcn_s_barrier();
  }
  #pragma unroll
  for (int m = 0; m < MR; ++m) {
    int row = m0 + wm * WROWS + m * 16 + (lane >> 4) * 4;
    int col = n0 + wn * 32 + (lane & 15);
    #pragma unroll
    for (int n = 0; n < 2; ++n)
      #pragma unroll
      for (int r = 0; r < 4; ++r)
        Cp[(size_t)(row + r) * N + col + n * 16] = acc[m][n][r];
  }
}

// ---------------- reduce for split-K gemm2: out = sum of 4 partials
__global__ __launch_bounds__(256) void k_reduce4(
    const float* __restrict__ p, float* __restrict__ out, int n) {
  int i = (blockIdx.x * 256 + threadIdx.x) * 4;
  float4 a = *(const float4*)(p + i);
  float4 b = *(const float4*)(p + n + i);
  float4 c = *(const float4*)(p + 2 * (size_t)n + i);
  float4 d = *(const float4*)(p + 3 * (size_t)n + i);
  float4 o;
  o.x = (a.x + b.x) + (c.x + d.x);
  o.y = (a.y + b.y) + (c.y + d.y);
  o.z = (a.z + b.z) + (c.z + d.z);
  o.w = (a.w + b.w) + (c.w + d.w);
  *(float4*)(out + i) = o;
}

// ---------------- K4: causal conv1d + silu (bf16 in/out) + dt/log-dA
__global__ __launch_bounds__(256) void k_conv(
    const short* __restrict__ xbc, const float* __restrict__ dtf,
    const float* __restrict__ cw, const float* __restrict__ cb,
    const float* __restrict__ A_log, const float* __restrict__ dt_bias,
    short* __restrict__ convo, float* __restrict__ dtb,
    float* __restrict__ ldab) {
  const int l0 = blockIdx.y * 64;
  if (blockIdx.x == CONVC / 256) {          // dt block
    #pragma unroll
    for (int i = 0; i < 16; ++i) {
      int idx = threadIdx.x + i * 256;
      int l = l0 + (idx >> 6), h = idx & 63;
      float v = dtf[l * 64 + h] + dt_bias[h];
      float dt = v > 20.f ? v : log1pf(expf(v));
      float lda = dt * (-expf(A_log[h]));
      dtb[h * LSEQ + l] = dt;
      ldab[h * LSEQ + l] = lda;
    }
    return;
  }
  const int c = blockIdx.x * 256 + threadIdx.x;
  const float w0 = cw[c*4+0], w1 = cw[c*4+1], w2 = cw[c*4+2], w3 = cw[c*4+3];
  const float bias = cb[c];
  float x0 = 0.f, x1 = 0.f, x2 = 0.f;
  if (l0 > 0) {
    x0 = bf2f(xbc[(size_t)(l0-3) * CONVC + c]);
    x1 = bf2f(xbc[(size_t)(l0-2) * CONVC + c]);
    x2 = bf2f(xbc[(size_t)(l0-1) * CONVC + c]);
  }
  for (int l = l0; l < l0 + 64; ++l) {
    float x3 = bf2f(xbc[(size_t)l * CONVC + c]);
    float accv = bias + x0*w0 + x1*w1 + x2*w2 + x3*w3;
    convo[(size_t)l * CONVC + c] = f2bf(siluf(accv));
    x0 = x1; x1 = x2; x2 = x3;
  }
}

// ---------------- K5a: SSD chunk kernel — per (chunk, head), all MFMA.
__global__ __launch_bounds__(256) void k_ssd(
    const short* __restrict__ convo, const float* __restrict__ dtb,
    const float* __restrict__ ldab, const float* __restrict__ Dp,
    short* __restrict__ ybuf, float* __restrict__ hend,
    float* __restrict__ Pbuf, float* __restrict__ cdbuf) {
  __shared__ __align__(16) short Xt[64 * 72];   // [d][l]
  __shared__ __align__(16) short Bs[64 * 72];   // [l][n]
  __shared__ __align__(16) short Cs[64 * 72];   // [l][n]
  __shared__ __align__(16) short Btw[64 * 72];  // [n][l], w-folded
  __shared__ __align__(16) short Ms[64 * 72];   // [i][j]
  __shared__ float s_s[64], s_dt[64], s_w[64];
  const int c = blockIdx.x, head = blockIdx.y;
  const int g = head >> 4;
  const int tid = threadIdx.x, lane = tid & 63, wid = tid >> 6;
  const int l0 = c * CL;
  const short* xbase = convo + (size_t)l0 * CONVC + head * HD;
  const short* Bbase = convo + (size_t)l0 * CONVC + INTER + g * NSTATE;
  const short* Cbase = convo + (size_t)l0 * CONVC + INTER + NG * NSTATE + g * NSTATE;

  if (tid < 64) {
    float ps = ldab[head * LSEQ + l0 + tid];
    #pragma unroll
    for (int o = 1; o < 64; o <<= 1) {
      float u = __shfl_up(ps, o);
      if (tid >= o) ps += u;
    }
    float dtv = dtb[head * LSEQ + l0 + tid];
    s_s[tid] = ps;
    s_dt[tid] = dtv;
    float s63 = __shfl(ps, 63);
    s_w[tid] = __expf(s63 - ps) * dtv;
    cdbuf[head * LSEQ + l0 + tid] = __expf(ps);
    if (tid == 63) Pbuf[c * NH + head] = __expf(ps);
  }
  #pragma unroll
  for (int rep = 0; rep < 4; ++rep) {
    int l = (tid >> 4) + rep * 16;
    int d = (tid & 15) * 4;
    size_t roff = (size_t)l * CONVC;
    short4v xv = *(const short4v*)(xbase + roff + d);
    Xt[(d + 0) * 72 + l] = xv.x;
    Xt[(d + 1) * 72 + l] = xv.y;
    Xt[(d + 2) * 72 + l] = xv.z;
    Xt[(d + 3) * 72 + l] = xv.w;
    *(short4v*)&Bs[l * 72 + d] = *(const short4v*)(Bbase + roff + d);
    *(short4v*)&Cs[l * 72 + d] = *(const short4v*)(Cbase + roff + d);
  }
  __syncthreads();
  #pragma unroll
  for (int rep = 0; rep < 16; ++rep) {
    int idx = rep * 256 + tid;
    int l = idx >> 6, n = idx & 63;
    Btw[n * 72 + l] = f2bf(bf2f(Bs[l * 72 + n]) * s_w[l]);
  }
  __syncthreads();
  const int lrow = lane & 15, lkb = (lane >> 4) * 8;
  f32x4 sacc[4] = {};
  f32x4 hacc[4] = {};
  #pragma unroll
  for (int kk = 0; kk < 2; ++kk) {
    bf16x8 ac = *(const bf16x8*)&Cs[(wid * 16 + lrow) * 72 + kk * 32 + lkb];
    bf16x8 ax = *(const bf16x8*)&Xt[(wid * 16 + lrow) * 72 + kk * 32 + lkb];
    #pragma unroll
    for (int t4 = 0; t4 < 4; ++t4) {
      bf16x8 bb = *(const bf16x8*)&Bs[(t4 * 16 + lrow) * 72 + kk * 32 + lkb];
      bf16x8 bw = *(const bf16x8*)&Btw[(t4 * 16 + lrow) * 72 + kk * 32 + lkb];
      sacc[t4] = __builtin_amdgcn_mfma_f32_16x16x32_bf16(ac, bb, sacc[t4], 0, 0, 0);
      hacc[t4] = __builtin_amdgcn_mfma_f32_16x16x32_bf16(ax, bw, hacc[t4], 0, 0, 0);
    }
  }
  float* hb = hend + ((size_t)c * NH + head) * (HD * NSTATE);
  #pragma unroll
  for (int t4 = 0; t4 < 4; ++t4) {
    int j = t4 * 16 + lrow;
    float sj = s_s[j], dtj = s_dt[j];
    #pragma unroll
    for (int r = 0; r < 4; ++r) {
      int i = wid * 16 + (lane >> 4) * 4 + r;
      float m = (j <= i) ? __expf(s_s[i] - sj) * dtj * sacc[t4][r] : 0.f;
      Ms[i * 72 + j] = f2bf(m);
      hb[i * NSTATE + j] = hacc[t4][r];
    }
  }
  __syncthreads();
  f32x4 yacc[4] = {};
  #pragma unroll
  for (int kk = 0; kk < 2; ++kk) {
    bf16x8 am = *(const bf16x8*)&Ms[(wid * 16 + lrow) * 72 + kk * 32 + lkb];
    #pragma unroll
    for (int t4 = 0; t4 < 4; ++t4) {
      bf16x8 bx = *(const bf16x8*)&Xt[(t4 * 16 + lrow) * 72 + kk * 32 + lkb];
      yacc[t4] = __builtin_amdgcn_mfma_f32_16x16x32_bf16(am, bx, yacc[t4], 0, 0, 0);
    }
  }
  const float Dv = Dp[head];
  #pragma unroll
  for (int t4 = 0; t4 < 4; ++t4) {
    int d = t4 * 16 + lrow;
    #pragma unroll
    for (int r = 0; r < 4; ++r) {
      int i = wid * 16 + (lane >> 4) * 4 + r;
      float xv = bf2f(Xt[d * 72 + i]);
      ybuf[(size_t)(l0 + i) * INTER + head * HD + d] = f2bf(yacc[t4][r] + xv * Dv);
    }
  }
}

// ---------------- K5b: combine chunk states
__global__ __launch_bounds__(256) void k_scan_combine(
    const float* __restrict__ hend, const float* __restrict__ Pbuf,
    float* __restrict__ hinbuf) {
  const int e = blockIdx.x * 256 + threadIdx.x;
  const int head = e >> 12;
  float h = 0.f;
  #pragma unroll
  for (int c = 1; c < NC; ++c) {
    h = Pbuf[(c - 1) * NH + head] * h + hend[(size_t)(c - 1) * NHDN + e];
    hinbuf[(size_t)c * NHDN + e] = h;
  }
}

// ---------------- K5c: y[l] += cd[l] * (C_l . h_in(c))   (ybuf bf16 RMW)
__global__ __launch_bounds__(256) void k_scan_fixup(
    const short* __restrict__ convo, const float* __restrict__ hinbuf,
    const float* __restrict__ cdbuf, short* __restrict__ ybuf) {
  __shared__ float sh[NSTATE][HD + 1];
  __shared__ float sc[CL][NSTATE];
  __shared__ float scd[CL];
  const int bid = blockIdx.x;
  const int c = (bid >> 6) + 1, head = bid & 63, g = head >> 4;
  const int t = threadIdx.x;
  #pragma unroll
  for (int i = 0; i < 16; ++i) {
    int idx = t + i * 256;
    int d = idx >> 6, n = idx & 63;
    sh[n][d] = hinbuf[(size_t)c * NHDN + head * (HD * NSTATE) + idx];
  }
  #pragma unroll
  for (int i = 0; i < 16; ++i) {
    int idx = t + i * 256;
    int ll = idx >> 6, n = idx & 63;
    sc[ll][n] = bf2f(convo[(size_t)(c * CL + ll) * CONVC + INTER + NG * NSTATE + g * NSTATE + n]);
  }
  if (t < CL) scd[t] = cdbuf[head * LSEQ + c * CL + t];
  __syncthreads();
  const int d = t & 63, w = t >> 6;
  #pragma unroll
  for (int i = 0; i < 4; ++i) {
    int l0 = i * 16 + w * 4;
    float a0 = 0.f, a1 = 0.f, a2 = 0.f, a3 = 0.f;
    for (int n = 0; n < NSTATE; ++n) {
      float hv = sh[n][d];
      a0 += hv * sc[l0 + 0][n];
      a1 += hv * sc[l0 + 1][n];
      a2 += hv * sc[l0 + 2][n];
      a3 += hv * sc[l0 + 3][n];
    }
    size_t base = (size_t)(c * CL + l0) * INTER + head * HD + d;
    ybuf[base + 0 * INTER] = f2bf(bf2f(ybuf[base + 0 * INTER]) + scd[l0 + 0] * a0);
    ybuf[base + 1 * INTER] = f2bf(bf2f(ybuf[base + 1 * INTER]) + scd[l0 + 1] * a1);
    ybuf[base + 2 * INTER] = f2bf(bf2f(ybuf[base + 2 * INTER]) + scd[l0 + 2] * a2);
    ybuf[base + 3 * INTER] = f2bf(bf2f(ybuf[base + 3 * INTER]) + scd[l0 + 3] * a3);
  }
}

// ---------------- K6: y2 = rmsnorm(y * silu(z)) * gn_w -> bf16 (y,z bf16)
__global__ __launch_bounds__(256) void k_gated_norm(
    const short* __restrict__ ybuf, const short* __restrict__ zbf,
    const float* __restrict__ gw, short* __restrict__ y2b) {
  __shared__ float sred[4];
  const int row = blockIdx.x, tid = threadIdx.x;
  const short4v* y4 = (const short4v*)(ybuf + (size_t)row * INTER);
  const short4v* z4 = (const short4v*)(zbf + (size_t)row * INTER);
  float g[16];
  float ss = 0.f;
  #pragma unroll
  for (int i = 0; i < 4; ++i) {
    short4v y = y4[tid + i * 256];
    short4v z = z4[tid + i * 256];
    float g0 = bf2f(y.x) * siluf(bf2f(z.x)), g1 = bf2f(y.y) * siluf(bf2f(z.y));
    float g2 = bf2f(y.z) * siluf(bf2f(z.z)), g3 = bf2f(y.w) * siluf(bf2f(z.w));
    g[i*4+0] = g0; g[i*4+1] = g1; g[i*4+2] = g2; g[i*4+3] = g3;
    ss += g0*g0 + g1*g1 + g2*g2 + g3*g3;
  }
  #pragma unroll
  for (int off = 32; off >= 1; off >>= 1) ss += __shfl_down(ss, off);
  if ((tid & 63) == 0) sred[tid >> 6] = ss;
  __syncthreads();
  float tot = sred[0] + sred[1] + sred[2] + sred[3];
  float rs = rsqrtf(tot / (float)INTER + EPS);
  #pragma unroll
  for (int i = 0; i < 4; ++i) {
    int e = (tid + i * 256) * 4;
    short4v s;
    s.x = f2bf(g[i*4+0] * rs * gw[e+0]);
    s.y = f2bf(g[i*4+1] * rs * gw[e+1]);
    s.z = f2bf(g[i*4+2] * rs * gw[e+2]);
    s.w = f2bf(g[i*4+3] * rs * gw[e+3]);
    *(short4v*)(y2b + (size_t)row * INTER + e) = s;
  }
}

extern "C" void kernel_launch(void* const* d_in, const int* in_sizes, int n_in,
                              void* d_out, int out_size, void* d_ws, size_t ws_size,
                              hipStream_t stream) {
  const float* hid     = (const float*)d_in[0];
  const float* res     = (const float*)d_in[1];
  const float* norm_w  = (const float*)d_in[2];
  const float* w1      = (const float*)d_in[3];   // H x PROJ (K x N)
  const float* cw      = (const float*)d_in[4];   // CONV x 4
  const float* cb      = (const float*)d_in[5];
  const float* A_log   = (const float*)d_in[6];
  const float* dt_bias = (const float*)d_in[7];
  const float* Dp      = (const float*)d_in[8];
  const float* gw      = (const float*)d_in[9];
  const float* w2      = (const float*)d_in[10];  // INTER x H (K x N)

  float* out = (float*)d_out;
  float* resid_out = out + (size_t)LSEQ * HDIM;

  char* ws = (char*)d_ws;
  short* hsb  = (short*)(ws);                    // 512x2048 bf16   (2 MB)
  // [2097152, 38010880): 35.9 MB window with SEQUENTIAL lifetimes:
  //   1) w1t (8768x2048 bf16) — written by transpose, read by gemm1t, dead after
  //   2) hend/hinbuf/Pbuf/cdbuf — written by ssd/combine (after gemm1t)
  //   3) p2 (4x512x2048 f32, 16.8MB) — gemm2 partials (after combine/fixup)
  short* w1t    = (short*)(ws + 2097152);
  float* hend   = (float*)(ws + 2097152);        // 8 MB
  float* p2     = (float*)(ws + 2097152);        // 16.8 MB
  float* hinbuf = (float*)(ws + 10485760);       // 8 MB
  float* Pbuf   = (float*)(ws + 18874368);
  float* cdbuf  = (float*)(ws + 18876416);       // 64x512 f32, head-major
  short* zbf  = (short*)(ws + 38010880);         // 512x4096 bf16   (4.2 MB)
  short* xbc  = (short*)(ws + 42205184);         // 512x4608 bf16   (4.7 MB)
  float* dtf  = (float*)(ws + 46923776);         // 512x64 f32
  short* convo= (short*)(ws + 55967744);         // 512x4608 bf16   (4.7 MB)
  float* dtb  = (float*)(ws + 65404928);         // 64x512 f32, head-major
  float* ldab = (float*)(ws + 65536000);         // 64x512 f32, head-major (log dA)
  short* ybuf = (short*)(ws + 65667072);         // 512x4096 bf16   (4.2 MB)
  short* y2b  = (short*)(ws + 74055680);         // 512x4096 bf16   (4.2 MB)
  short* w2t  = (short*)(ws + 78249984);         // 2048x4096 bf16  (16.8 MB)

  k_add_rmsnorm<<<LSEQ, 256, 0, stream>>>(hid, res, norm_w, resid_out, hsb);
  k_transpose_cvt<<<dim3(PROJC/32, HDIM/32), 256, 0, stream>>>(w1, w1t, HDIM, PROJC);
  k_gemm1t<<<(LSEQ/128)*(PROJC/64), 256, 0, stream>>>(hsb, w1t, zbf, xbc, dtf);
  k_conv<<<dim3(CONVC/256 + 1, NC), 256, 0, stream>>>(xbc, dtf, cw, cb, A_log, dt_bias, convo, dtb, ldab);
  k_ssd<<<dim3(NC, NH), 256, 0, stream>>>(convo, dtb, ldab, Dp, ybuf, hend, Pbuf, cdbuf);
  k_scan_combine<<<NHDN/256, 256, 0, stream>>>(hend, Pbuf, hinbuf);
  k_scan_fixup<<<(NC-1)*NH, 256, 0, stream>>>(convo, hinbuf, cdbuf, ybuf);
  k_gated_norm<<<LSEQ, 256, 0, stream>>>(ybuf, zbf, gw, y2b);
  k_transpose_cvt<<<dim3(HDIM/32, INTER/32), 256, 0, stream>>>(w2, w2t, INTER, HDIM);
  k_gemm_bf16<64, 4><<<(LSEQ/64)*(HDIM/64)*4, 256, 0, stream>>>(y2b, w2t, p2, LSEQ, HDIM, INTER);
  k_reduce4<<<LSEQ*HDIM/1024, 256, 0, stream>>>(p2, out, LSEQ*HDIM);
}

// Round 16
// 136.275 us; speedup vs baseline: 1.0099x; 1.0099x over previous
//
#include <hip/hip_runtime.h>
#include <stdint.h>

#define LSEQ 512
#define HDIM 2048
#define NH 64
#define HD 64
#define INTER 4096
#define NG 4
#define NSTATE 64
#define CONVC 4608
#define PROJC 8768
#define EPS 1e-5f
#define CL 64
#define NC 8
#define NHDN (NH * HD * NSTATE)

typedef __attribute__((ext_vector_type(8))) short bf16x8;
typedef __attribute__((ext_vector_type(4))) short short4v;
typedef __attribute__((ext_vector_type(4))) float f32x4;

__device__ __forceinline__ short f2bf(float f) {
  union { float f; uint32_t u; } v; v.f = f;
  uint32_t r = v.u + 0x7FFFu + ((v.u >> 16) & 1u);
  return (short)(r >> 16);
}

// packed 2xf32 -> u32(2xbf16), RNE (same rounding as f2bf)
__device__ __forceinline__ uint32_t cvt_pk_bf16(float lo, float hi) {
  uint32_t r;
  asm("v_cvt_pk_bf16_f32 %0, %1, %2" : "=v"(r) : "v"(lo), "v"(hi));
  return r;
}

__device__ __forceinline__ float bf2f(short s) {
  union { uint32_t u; float f; } v; v.u = ((uint32_t)(uint16_t)s) << 16;
  return v.f;
}

__device__ __forceinline__ float siluf(float v) {
  return v / (1.f + expf(-v));
}

// bijective XCD-chunked swizzle (m204)
__device__ __forceinline__ int xcd_swizzle(int orig, int nwg) {
  int q = nwg >> 3, r = nwg & 7;
  int xcd = orig & 7, idx = orig >> 3;
  return (xcd < r ? xcd * (q + 1) : r * (q + 1) + (xcd - r) * q) + idx;
}

// ---------------- K1: x = h + r ; residual out ; hs = rmsnorm(x)*w -> bf16
__global__ __launch_bounds__(256) void k_add_rmsnorm(
    const float* __restrict__ hid, const float* __restrict__ res,
    const float* __restrict__ w, float* __restrict__ resid_out,
    short* __restrict__ hsb) {
  __shared__ float sred[4];
  const int row = blockIdx.x, tid = threadIdx.x;
  const float4* h4 = (const float4*)(hid + (size_t)row * HDIM);
  const float4* r4 = (const float4*)(res + (size_t)row * HDIM);
  float4* ro4 = (float4*)(resid_out + (size_t)row * HDIM);
  float4 a0 = h4[tid], b0 = r4[tid];
  float4 a1 = h4[tid + 256], b1 = r4[tid + 256];
  float4 xa, xb;
  xa.x = a0.x + b0.x; xa.y = a0.y + b0.y; xa.z = a0.z + b0.z; xa.w = a0.w + b0.w;
  xb.x = a1.x + b1.x; xb.y = a1.y + b1.y; xb.z = a1.z + b1.z; xb.w = a1.w + b1.w;
  ro4[tid] = xa; ro4[tid + 256] = xb;
  float ss = xa.x*xa.x + xa.y*xa.y + xa.z*xa.z + xa.w*xa.w
           + xb.x*xb.x + xb.y*xb.y + xb.z*xb.z + xb.w*xb.w;
  #pragma unroll
  for (int off = 32; off >= 1; off >>= 1) ss += __shfl_down(ss, off);
  if ((tid & 63) == 0) sred[tid >> 6] = ss;
  __syncthreads();
  float tot = sred[0] + sred[1] + sred[2] + sred[3];
  float rs = rsqrtf(tot / (float)HDIM + EPS);
  int e0 = tid * 4, e1 = (tid + 256) * 4;
  short4v s0, s1;
  s0.x = f2bf(xa.x * rs * w[e0+0]); s0.y = f2bf(xa.y * rs * w[e0+1]);
  s0.z = f2bf(xa.z * rs * w[e0+2]); s0.w = f2bf(xa.w * rs * w[e0+3]);
  s1.x = f2bf(xb.x * rs * w[e1+0]); s1.y = f2bf(xb.y * rs * w[e1+1]);
  s1.z = f2bf(xb.z * rs * w[e1+2]); s1.w = f2bf(xb.w * rs * w[e1+3]);
  *(short4v*)(hsb + (size_t)row * HDIM + e0) = s0;
  *(short4v*)(hsb + (size_t)row * HDIM + e1) = s1;
}

// ---------------- K2: dst[c][r] = bf16(src[r][c])   src: R x C f32
__global__ __launch_bounds__(256) void k_transpose_cvt(
    const float* __restrict__ src, short* __restrict__ dst, int R, int C) {
  __shared__ float tile[32][33];
  const int tx = threadIdx.x & 31, ty = threadIdx.x >> 5;
  const int c0 = blockIdx.x * 32, r0 = blockIdx.y * 32;
  #pragma unroll
  for (int i = 0; i < 4; ++i)
    tile[ty + i*8][tx] = src[(size_t)(r0 + ty + i*8) * C + c0 + tx];
  __syncthreads();
  #pragma unroll
  for (int i = 0; i < 4; ++i)
    dst[(size_t)(c0 + ty + i*8) * R + r0 + tx] = f2bf(tile[tx][ty + i*8]);
}

// ---------------- GEMM1: p1[zi] = hs(bf16) * w1(f32, K x N natural) halves
// Fused f32->bf16 B-conversion, single-buffer lB (40KB LDS), split-K=2.
__global__ __launch_bounds__(256) void k_gemm1(
    const short* __restrict__ A, const float* __restrict__ Bw,
    float* __restrict__ P) {
  constexpr int BM = 128, MR = 4, WROWS = 64, KS = 2;
  const int M = LSEQ, N = PROJC, K = HDIM;
  __shared__ short lA[2][BM * 64];
  __shared__ short lB[64 * 64];
  const int tid = threadIdx.x, lane = tid & 63, wid = tid >> 6;

  const int NMB = M / BM;
  const int nwg = NMB * (N / 64) * KS;
  int wg = xcd_swizzle(blockIdx.x, nwg);
  const int mi = wg % NMB;
  int rest = wg / NMB;
  const int zi = rest & 1;
  const int ni = rest >> 1;
  const int m0 = mi * BM, n0 = ni * 64;
  const int wm = wid >> 1, wn = wid & 1;
  const int kbase = zi * (K / KS);
  float* Pp = P + (size_t)zi * M * N;

  const int lrow8 = lane >> 3;
  const int cswz = ((lane & 7) ^ lrow8) * 8;

  auto stageA = [&](int buf, int kt) {
    #pragma unroll
    for (int r2 = 0; r2 < MR; ++r2) {
      int idx = r2 * 4 + wid;
      __builtin_amdgcn_global_load_lds(
          (const __attribute__((address_space(1))) int*)(A + (size_t)(m0 + idx * 8 + lrow8) * K + kt + cswz),
          (__attribute__((address_space(3))) int*)(&lA[buf][idx * 512]),
          16, 0, 0);
    }
  };

  float breg[16];
  auto loadB = [&](int kt) {
    #pragma unroll
    for (int r = 0; r < 2; ++r)
      #pragma unroll
      for (int j = 0; j < 8; ++j)
        breg[r * 8 + j] = Bw[(size_t)(kt + wid * 16 + r * 8 + j) * N + n0 + lane];
  };
  auto writeB = [&]() {
    #pragma unroll
    for (int r = 0; r < 2; ++r) {
      uint4 v;
      v.x = cvt_pk_bf16(breg[r*8+0], breg[r*8+1]);
      v.y = cvt_pk_bf16(breg[r*8+2], breg[r*8+3]);
      v.z = cvt_pk_bf16(breg[r*8+4], breg[r*8+5]);
      v.w = cvt_pk_bf16(breg[r*8+6], breg[r*8+7]);
      int ko = wid * 2 + r;
      *(uint4*)&lB[lane * 64 + ((ko ^ (lane & 7)) << 3)] = v;
    }
  };

  f32x4 acc[MR][2] = {};
  const int lrow = lane & 15, lkb = (lane >> 4) * 8;
  const int NT = (K / KS) >> 6;   // 16
  loadB(kbase);
  stageA(0, kbase);
  writeB();
  asm volatile("s_waitcnt vmcnt(0)" ::: "memory");
  asm volatile("s_waitcnt lgkmcnt(0)" ::: "memory");
  __builtin_amdgcn_s_barrier();
  for (int t = 0; t < NT; ++t) {
    int cur = t & 1;
    if (t + 1 < NT) {
      loadB(kbase + (t + 1) * 64);
      stageA(cur ^ 1, kbase + (t + 1) * 64);
    }
    #pragma unroll
    for (int kk = 0; kk < 2; ++kk) {
      bf16x8 a[MR], b[2];
      #pragma unroll
      for (int m = 0; m < MR; ++m) {
        int row = wm * WROWS + m * 16 + lrow;
        int colel = (kk * 32 + lkb) ^ ((row & 7) << 3);
        a[m] = *(const bf16x8*)&lA[cur][row * 64 + colel];
      }
      #pragma unroll
      for (int n = 0; n < 2; ++n) {
        int row = wn * 32 + n * 16 + lrow;
        int colel = (kk * 32 + lkb) ^ ((row & 7) << 3);
        b[n] = *(const bf16x8*)&lB[row * 64 + colel];
      }
      #pragma unroll
      for (int m = 0; m < MR; ++m)
        #pragma unroll
        for (int n = 0; n < 2; ++n)
          acc[m][n] = __builtin_amdgcn_mfma_f32_16x16x32_bf16(a[m], b[n], acc[m][n], 0, 0, 0);
    }
    __builtin_amdgcn_s_barrier();          // all waves done reading lB
    if (t + 1 < NT) writeB();              // auto-waits B loads only (counted)
    asm volatile("s_waitcnt vmcnt(0)" ::: "memory");
    asm volatile("s_waitcnt lgkmcnt(0)" ::: "memory");
    __builtin_amdgcn_s_barrier();
  }
  #pragma unroll
  for (int m = 0; m < MR; ++m) {
    int row = m0 + wm * WROWS + m * 16 + (lane >> 4) * 4;
    #pragma unroll
    for (int n = 0; n < 2; ++n) {
      int col = n0 + wn * 32 + n * 16 + (lane & 15);
      #pragma unroll
      for (int r = 0; r < 4; ++r)
        Pp[(size_t)(row + r) * N + col] = acc[m][n][r];
    }
  }
}

// ---------------- reduce p1[0]+p1[1] and route to zbf/xbc/dtf
__global__ __launch_bounds__(256) void k_reduce_route(
    const float* __restrict__ p, short* __restrict__ zbf,
    short* __restrict__ xbc, float* __restrict__ dtf) {
  const int i = (blockIdx.x * 256 + threadIdx.x) * 4;
  float4 a = *(const float4*)(p + i);
  float4 b = *(const float4*)(p + (size_t)LSEQ * PROJC + i);
  float4 o;
  o.x = a.x + b.x; o.y = a.y + b.y; o.z = a.z + b.z; o.w = a.w + b.w;
  const int row = i / PROJC, col = i % PROJC;
  if (col < INTER) {
    short4v s;
    s.x = f2bf(o.x); s.y = f2bf(o.y); s.z = f2bf(o.z); s.w = f2bf(o.w);
    *(short4v*)(zbf + (size_t)row * INTER + col) = s;
  } else if (col < INTER + CONVC) {
    short4v s;
    s.x = f2bf(o.x); s.y = f2bf(o.y); s.z = f2bf(o.z); s.w = f2bf(o.w);
    *(short4v*)(xbc + (size_t)row * CONVC + (col - INTER)) = s;
  } else {
    *(float4*)(dtf + row * 64 + (col - INTER - CONVC)) = o;
  }
}

// ---------------- GEMM-bf16 (gemm2): C = A(bf16) * B(bf16, N x K)^T
template <int BM, int KS>
__global__ __launch_bounds__(256) void k_gemm_bf16(
    const short* __restrict__ A, const short* __restrict__ B,
    float* __restrict__ C, int M, int N, int K) {
  __shared__ short lA[2][BM * 64];
  __shared__ short lB[2][64 * 64];
  const int tid = threadIdx.x;
  const int lane = tid & 63, wid = tid >> 6;
  constexpr int MR = BM / 32;
  constexpr int WROWS = BM / 2;

  const int NMB = M / BM, NNB = N / 64;
  const int nwg = NMB * NNB * KS;
  int wg = xcd_swizzle(blockIdx.x, nwg);
  const int mi = wg % NMB;
  int rest = wg / NMB;
  const int zi = (KS > 1) ? (rest % KS) : 0;
  const int ni = (KS > 1) ? (rest / KS) : rest;
  const int m0 = mi * BM, n0 = ni * 64;
  const int wm = wid >> 1, wn = wid & 1;

  const int lrow8 = lane >> 3;
  const int cswz = ((lane & 7) ^ lrow8) * 8;

  const int Kc = K / KS;
  const int kbase = zi * Kc;
  float* Cp = C + (size_t)zi * M * N;

  auto stage = [&](int buf, int kt) {
    #pragma unroll
    for (int r2 = 0; r2 < MR; ++r2) {
      int idx = r2 * 4 + wid;
      __builtin_amdgcn_global_load_lds(
          (const __attribute__((address_space(1))) int*)(A + (size_t)(m0 + idx * 8 + lrow8) * K + kt + cswz),
          (__attribute__((address_space(3))) int*)(&lA[buf][idx * 512]),
          16, 0, 0);
    }
    #pragma unroll
    for (int r2 = 0; r2 < 2; ++r2) {
      int idx = r2 * 4 + wid;
      __builtin_amdgcn_global_load_lds(
          (const __attribute__((address_space(1))) int*)(B + (size_t)(n0 + idx * 8 + lrow8) * K + kt + cswz),
          (__attribute__((address_space(3))) int*)(&lB[buf][idx * 512]),
          16, 0, 0);
    }
  };

  f32x4 acc[MR][2] = {};
  const int lrow = lane & 15, lkb = (lane >> 4) * 8;
  const int NT = Kc >> 6;
  stage(0, kbase);
  for (int t = 0; t < NT; ++t) {
    int cur = t & 1;
    if (t + 1 < NT) {
      stage(cur ^ 1, kbase + (t + 1) * 64);
      if constexpr (MR == 2) asm volatile("s_waitcnt vmcnt(4)" ::: "memory");
      else                   asm volatile("s_waitcnt vmcnt(6)" ::: "memory");
    } else {
      asm volatile("s_waitcnt vmcnt(0)" ::: "memory");
    }
    __builtin_amdgcn_s_barrier();
    #pragma unroll
    for (int kk = 0; kk < 2; ++kk) {
      bf16x8 a[MR], b[2];
      #pragma unroll
      for (int m = 0; m < MR; ++m) {
        int row = wm * WROWS + m * 16 + lrow;
        int colel = (kk * 32 + lkb) ^ ((row & 7) << 3);
        a[m] = *(const bf16x8*)&lA[cur][row * 64 + colel];
      }
      #pragma unroll
      for (int n = 0; n < 2; ++n) {
        int row = wn * 32 + n * 16 + lrow;
        int colel = (kk * 32 + lkb) ^ ((row & 7) << 3);
        b[n] = *(const bf16x8*)&lB[cur][row * 64 + colel];
      }
      #pragma unroll
      for (int m = 0; m < MR; ++m)
        #pragma unroll
        for (int n = 0; n < 2; ++n)
          acc[m][n] = __builtin_amdgcn_mfma_f32_16x16x32_bf16(a[m], b[n], acc[m][n], 0, 0, 0);
    }
    __builtin_amdgcn_s_barrier();
  }
  #pragma unroll
  for (int m = 0; m < MR; ++m) {
    int row = m0 + wm * WROWS + m * 16 + (lane >> 4) * 4;
    int col = n0 + wn * 32 + (lane & 15);
    #pragma unroll
    for (int n = 0; n < 2; ++n)
      #pragma unroll
      for (int r = 0; r < 4; ++r)
        Cp[(size_t)(row + r) * N + col + n * 16] = acc[m][n][r];
  }
}

// ---------------- reduce for split-K gemm2: out = sum of 4 partials
__global__ __launch_bounds__(256) void k_reduce4(
    const float* __restrict__ p, float* __restrict__ out, int n) {
  int i = (blockIdx.x * 256 + threadIdx.x) * 4;
  float4 a = *(const float4*)(p + i);
  float4 b = *(const float4*)(p + n + i);
  float4 c = *(const float4*)(p + 2 * (size_t)n + i);
  float4 d = *(const float4*)(p + 3 * (size_t)n + i);
  float4 o;
  o.x = (a.x + b.x) + (c.x + d.x);
  o.y = (a.y + b.y) + (c.y + d.y);
  o.z = (a.z + b.z) + (c.z + d.z);
  o.w = (a.w + b.w) + (c.w + d.w);
  *(float4*)(out + i) = o;
}

// ---------------- K4: causal conv1d + silu (bf16 in/out) + dt/log-dA
__global__ __launch_bounds__(256) void k_conv(
    const short* __restrict__ xbc, const float* __restrict__ dtf,
    const float* __restrict__ cw, const float* __restrict__ cb,
    const float* __restrict__ A_log, const float* __restrict__ dt_bias,
    short* __restrict__ convo, float* __restrict__ dtb,
    float* __restrict__ ldab) {
  const int l0 = blockIdx.y * 64;
  if (blockIdx.x == CONVC / 256) {          // dt block
    #pragma unroll
    for (int i = 0; i < 16; ++i) {
      int idx = threadIdx.x + i * 256;
      int l = l0 + (idx >> 6), h = idx & 63;
      float v = dtf[l * 64 + h] + dt_bias[h];
      float dt = v > 20.f ? v : log1pf(expf(v));
      float lda = dt * (-expf(A_log[h]));
      dtb[h * LSEQ + l] = dt;
      ldab[h * LSEQ + l] = lda;
    }
    return;
  }
  const int c = blockIdx.x * 256 + threadIdx.x;
  const float w0 = cw[c*4+0], w1 = cw[c*4+1], w2 = cw[c*4+2], w3 = cw[c*4+3];
  const float bias = cb[c];
  float x0 = 0.f, x1 = 0.f, x2 = 0.f;
  if (l0 > 0) {
    x0 = bf2f(xbc[(size_t)(l0-3) * CONVC + c]);
    x1 = bf2f(xbc[(size_t)(l0-2) * CONVC + c]);
    x2 = bf2f(xbc[(size_t)(l0-1) * CONVC + c]);
  }
  for (int l = l0; l < l0 + 64; ++l) {
    float x3 = bf2f(xbc[(size_t)l * CONVC + c]);
    float accv = bias + x0*w0 + x1*w1 + x2*w2 + x3*w3;
    convo[(size_t)l * CONVC + c] = f2bf(siluf(accv));
    x0 = x1; x1 = x2; x2 = x3;
  }
}

// ---------------- K5a: SSD chunk kernel — per (chunk, head), all MFMA.
__global__ __launch_bounds__(256) void k_ssd(
    const short* __restrict__ convo, const float* __restrict__ dtb,
    const float* __restrict__ ldab, const float* __restrict__ Dp,
    short* __restrict__ ybuf, float* __restrict__ hend,
    float* __restrict__ Pbuf, float* __restrict__ cdbuf) {
  __shared__ __align__(16) short Xt[64 * 72];   // [d][l]
  __shared__ __align__(16) short Bs[64 * 72];   // [l][n]
  __shared__ __align__(16) short Cs[64 * 72];   // [l][n]
  __shared__ __align__(16) short Btw[64 * 72];  // [n][l], w-folded
  __shared__ __align__(16) short Ms[64 * 72];   // [i][j]
  __shared__ float s_s[64], s_dt[64], s_w[64];
  const int c = blockIdx.x, head = blockIdx.y;
  const int g = head >> 4;
  const int tid = threadIdx.x, lane = tid & 63, wid = tid >> 6;
  const int l0 = c * CL;
  const short* xbase = convo + (size_t)l0 * CONVC + head * HD;
  const short* Bbase = convo + (size_t)l0 * CONVC + INTER + g * NSTATE;
  const short* Cbase = convo + (size_t)l0 * CONVC + INTER + NG * NSTATE + g * NSTATE;

  if (tid < 64) {
    float ps = ldab[head * LSEQ + l0 + tid];
    #pragma unroll
    for (int o = 1; o < 64; o <<= 1) {
      float u = __shfl_up(ps, o);
      if (tid >= o) ps += u;
    }
    float dtv = dtb[head * LSEQ + l0 + tid];
    s_s[tid] = ps;
    s_dt[tid] = dtv;
    float s63 = __shfl(ps, 63);
    s_w[tid] = __expf(s63 - ps) * dtv;
    cdbuf[head * LSEQ + l0 + tid] = __expf(ps);
    if (tid == 63) Pbuf[c * NH + head] = __expf(ps);
  }
  #pragma unroll
  for (int rep = 0; rep < 4; ++rep) {
    int l = (tid >> 4) + rep * 16;
    int d = (tid & 15) * 4;
    size_t roff = (size_t)l * CONVC;
    short4v xv = *(const short4v*)(xbase + roff + d);
    Xt[(d + 0) * 72 + l] = xv.x;
    Xt[(d + 1) * 72 + l] = xv.y;
    Xt[(d + 2) * 72 + l] = xv.z;
    Xt[(d + 3) * 72 + l] = xv.w;
    *(short4v*)&Bs[l * 72 + d] = *(const short4v*)(Bbase + roff + d);
    *(short4v*)&Cs[l * 72 + d] = *(const short4v*)(Cbase + roff + d);
  }
  __syncthreads();
  #pragma unroll
  for (int rep = 0; rep < 16; ++rep) {
    int idx = rep * 256 + tid;
    int l = idx >> 6, n = idx & 63;
    Btw[n * 72 + l] = f2bf(bf2f(Bs[l * 72 + n]) * s_w[l]);
  }
  __syncthreads();
  const int lrow = lane & 15, lkb = (lane >> 4) * 8;
  f32x4 sacc[4] = {};
  f32x4 hacc[4] = {};
  #pragma unroll
  for (int kk = 0; kk < 2; ++kk) {
    bf16x8 ac = *(const bf16x8*)&Cs[(wid * 16 + lrow) * 72 + kk * 32 + lkb];
    bf16x8 ax = *(const bf16x8*)&Xt[(wid * 16 + lrow) * 72 + kk * 32 + lkb];
    #pragma unroll
    for (int t4 = 0; t4 < 4; ++t4) {
      bf16x8 bb = *(const bf16x8*)&Bs[(t4 * 16 + lrow) * 72 + kk * 32 + lkb];
      bf16x8 bw = *(const bf16x8*)&Btw[(t4 * 16 + lrow) * 72 + kk * 32 + lkb];
      sacc[t4] = __builtin_amdgcn_mfma_f32_16x16x32_bf16(ac, bb, sacc[t4], 0, 0, 0);
      hacc[t4] = __builtin_amdgcn_mfma_f32_16x16x32_bf16(ax, bw, hacc[t4], 0, 0, 0);
    }
  }
  float* hb = hend + ((size_t)c * NH + head) * (HD * NSTATE);
  #pragma unroll
  for (int t4 = 0; t4 < 4; ++t4) {
    int j = t4 * 16 + lrow;
    float sj = s_s[j], dtj = s_dt[j];
    #pragma unroll
    for (int r = 0; r < 4; ++r) {
      int i = wid * 16 + (lane >> 4) * 4 + r;
      float m = (j <= i) ? __expf(s_s[i] - sj) * dtj * sacc[t4][r] : 0.f;
      Ms[i * 72 + j] = f2bf(m);
      hb[i * NSTATE + j] = hacc[t4][r];
    }
  }
  __syncthreads();
  f32x4 yacc[4] = {};
  #pragma unroll
  for (int kk = 0; kk < 2; ++kk) {
    bf16x8 am = *(const bf16x8*)&Ms[(wid * 16 + lrow) * 72 + kk * 32 + lkb];
    #pragma unroll
    for (int t4 = 0; t4 < 4; ++t4) {
      bf16x8 bx = *(const bf16x8*)&Xt[(t4 * 16 + lrow) * 72 + kk * 32 + lkb];
      yacc[t4] = __builtin_amdgcn_mfma_f32_16x16x32_bf16(am, bx, yacc[t4], 0, 0, 0);
    }
  }
  const float Dv = Dp[head];
  #pragma unroll
  for (int t4 = 0; t4 < 4; ++t4) {
    int d = t4 * 16 + lrow;
    #pragma unroll
    for (int r = 0; r < 4; ++r) {
      int i = wid * 16 + (lane >> 4) * 4 + r;
      float xv = bf2f(Xt[d * 72 + i]);
      ybuf[(size_t)(l0 + i) * INTER + head * HD + d] = f2bf(yacc[t4][r] + xv * Dv);
    }
  }
}

// ---------------- K5b: combine chunk states
__global__ __launch_bounds__(256) void k_scan_combine(
    const float* __restrict__ hend, const float* __restrict__ Pbuf,
    float* __restrict__ hinbuf) {
  const int e = blockIdx.x * 256 + threadIdx.x;
  const int head = e >> 12;
  float h = 0.f;
  #pragma unroll
  for (int c = 1; c < NC; ++c) {
    h = Pbuf[(c - 1) * NH + head] * h + hend[(size_t)(c - 1) * NHDN + e];
    hinbuf[(size_t)c * NHDN + e] = h;
  }
}

// ---------------- K5c: y[l] += cd[l] * (C_l . h_in(c))   (ybuf bf16 RMW)
__global__ __launch_bounds__(256) void k_scan_fixup(
    const short* __restrict__ convo, const float* __restrict__ hinbuf,
    const float* __restrict__ cdbuf, short* __restrict__ ybuf) {
  __shared__ float sh[NSTATE][HD + 1];
  __shared__ float sc[CL][NSTATE];
  __shared__ float scd[CL];
  const int bid = blockIdx.x;
  const int c = (bid >> 6) + 1, head = bid & 63, g = head >> 4;
  const int t = threadIdx.x;
  #pragma unroll
  for (int i = 0; i < 16; ++i) {
    int idx = t + i * 256;
    int d = idx >> 6, n = idx & 63;
    sh[n][d] = hinbuf[(size_t)c * NHDN + head * (HD * NSTATE) + idx];
  }
  #pragma unroll
  for (int i = 0; i < 16; ++i) {
    int idx = t + i * 256;
    int ll = idx >> 6, n = idx & 63;
    sc[ll][n] = bf2f(convo[(size_t)(c * CL + ll) * CONVC + INTER + NG * NSTATE + g * NSTATE + n]);
  }
  if (t < CL) scd[t] = cdbuf[head * LSEQ + c * CL + t];
  __syncthreads();
  const int d = t & 63, w = t >> 6;
  #pragma unroll
  for (int i = 0; i < 4; ++i) {
    int l0 = i * 16 + w * 4;
    float a0 = 0.f, a1 = 0.f, a2 = 0.f, a3 = 0.f;
    for (int n = 0; n < NSTATE; ++n) {
      float hv = sh[n][d];
      a0 += hv * sc[l0 + 0][n];
      a1 += hv * sc[l0 + 1][n];
      a2 += hv * sc[l0 + 2][n];
      a3 += hv * sc[l0 + 3][n];
    }
    size_t base = (size_t)(c * CL + l0) * INTER + head * HD + d;
    ybuf[base + 0 * INTER] = f2bf(bf2f(ybuf[base + 0 * INTER]) + scd[l0 + 0] * a0);
    ybuf[base + 1 * INTER] = f2bf(bf2f(ybuf[base + 1 * INTER]) + scd[l0 + 1] * a1);
    ybuf[base + 2 * INTER] = f2bf(bf2f(ybuf[base + 2 * INTER]) + scd[l0 + 2] * a2);
    ybuf[base + 3 * INTER] = f2bf(bf2f(ybuf[base + 3 * INTER]) + scd[l0 + 3] * a3);
  }
}

// ---------------- K6: y2 = rmsnorm(y * silu(z)) * gn_w -> bf16 (y,z bf16)
__global__ __launch_bounds__(256) void k_gated_norm(
    const short* __restrict__ ybuf, const short* __restrict__ zbf,
    const float* __restrict__ gw, short* __restrict__ y2b) {
  __shared__ float sred[4];
  const int row = blockIdx.x, tid = threadIdx.x;
  const short4v* y4 = (const short4v*)(ybuf + (size_t)row * INTER);
  const short4v* z4 = (const short4v*)(zbf + (size_t)row * INTER);
  float g[16];
  float ss = 0.f;
  #pragma unroll
  for (int i = 0; i < 4; ++i) {
    short4v y = y4[tid + i * 256];
    short4v z = z4[tid + i * 256];
    float g0 = bf2f(y.x) * siluf(bf2f(z.x)), g1 = bf2f(y.y) * siluf(bf2f(z.y));
    float g2 = bf2f(y.z) * siluf(bf2f(z.z)), g3 = bf2f(y.w) * siluf(bf2f(z.w));
    g[i*4+0] = g0; g[i*4+1] = g1; g[i*4+2] = g2; g[i*4+3] = g3;
    ss += g0*g0 + g1*g1 + g2*g2 + g3*g3;
  }
  #pragma unroll
  for (int off = 32; off >= 1; off >>= 1) ss += __shfl_down(ss, off);
  if ((tid & 63) == 0) sred[tid >> 6] = ss;
  __syncthreads();
  float tot = sred[0] + sred[1] + sred[2] + sred[3];
  float rs = rsqrtf(tot / (float)INTER + EPS);
  #pragma unroll
  for (int i = 0; i < 4; ++i) {
    int e = (tid + i * 256) * 4;
    short4v s;
    s.x = f2bf(g[i*4+0] * rs * gw[e+0]);
    s.y = f2bf(g[i*4+1] * rs * gw[e+1]);
    s.z = f2bf(g[i*4+2] * rs * gw[e+2]);
    s.w = f2bf(g[i*4+3] * rs * gw[e+3]);
    *(short4v*)(y2b + (size_t)row * INTER + e) = s;
  }
}

extern "C" void kernel_launch(void* const* d_in, const int* in_sizes, int n_in,
                              void* d_out, int out_size, void* d_ws, size_t ws_size,
                              hipStream_t stream) {
  const float* hid     = (const float*)d_in[0];
  const float* res     = (const float*)d_in[1];
  const float* norm_w  = (const float*)d_in[2];
  const float* w1      = (const float*)d_in[3];   // H x PROJ (K x N)
  const float* cw      = (const float*)d_in[4];   // CONV x 4
  const float* cb      = (const float*)d_in[5];
  const float* A_log   = (const float*)d_in[6];
  const float* dt_bias = (const float*)d_in[7];
  const float* Dp      = (const float*)d_in[8];
  const float* gw      = (const float*)d_in[9];
  const float* w2      = (const float*)d_in[10];  // INTER x H (K x N)

  float* out = (float*)d_out;
  float* resid_out = out + (size_t)LSEQ * HDIM;

  char* ws = (char*)d_ws;
  short* hsb  = (short*)(ws);                    // 512x2048 bf16   (2 MB)
  // [2097152, 38010880): 35.9 MB window, SEQUENTIAL lifetimes:
  //   1) p1 (2x512x8768 f32, 35.9MB) — gemm1 partials, dead after reduce_route
  //   2) hend/hinbuf/Pbuf/cdbuf — ssd/combine (after reduce_route)
  //   3) p2 (4x512x2048 f32, 16.8MB) — gemm2 partials (after combine/fixup)
  float* p1     = (float*)(ws + 2097152);
  float* hend   = (float*)(ws + 2097152);        // 8 MB
  float* p2     = (float*)(ws + 2097152);        // 16.8 MB
  float* hinbuf = (float*)(ws + 10485760);       // 8 MB
  float* Pbuf   = (float*)(ws + 18874368);
  float* cdbuf  = (float*)(ws + 18876416);       // 64x512 f32, head-major
  short* zbf  = (short*)(ws + 38010880);         // 512x4096 bf16   (4.2 MB)
  short* xbc  = (short*)(ws + 42205184);         // 512x4608 bf16   (4.7 MB)
  float* dtf  = (float*)(ws + 46923776);         // 512x64 f32
  short* convo= (short*)(ws + 55967744);         // 512x4608 bf16   (4.7 MB)
  float* dtb  = (float*)(ws + 65404928);         // 64x512 f32, head-major
  float* ldab = (float*)(ws + 65536000);         // 64x512 f32, head-major (log dA)
  short* ybuf = (short*)(ws + 65667072);         // 512x4096 bf16   (4.2 MB)
  short* y2b  = (short*)(ws + 74055680);         // 512x4096 bf16   (4.2 MB)
  short* w2t  = (short*)(ws + 78249984);         // 2048x4096 bf16  (16.8 MB)

  k_add_rmsnorm<<<LSEQ, 256, 0, stream>>>(hid, res, norm_w, resid_out, hsb);
  k_gemm1<<<(LSEQ/128)*(PROJC/64)*2, 256, 0, stream>>>(hsb, w1, p1);
  k_reduce_route<<<LSEQ*PROJC/1024, 256, 0, stream>>>(p1, zbf, xbc, dtf);
  k_conv<<<dim3(CONVC/256 + 1, NC), 256, 0, stream>>>(xbc, dtf, cw, cb, A_log, dt_bias, convo, dtb, ldab);
  k_ssd<<<dim3(NC, NH), 256, 0, stream>>>(convo, dtb, ldab, Dp, ybuf, hend, Pbuf, cdbuf);
  k_scan_combine<<<NHDN/256, 256, 0, stream>>>(hend, Pbuf, hinbuf);
  k_scan_fixup<<<(NC-1)*NH, 256, 0, stream>>>(convo, hinbuf, cdbuf, ybuf);
  k_gated_norm<<<LSEQ, 256, 0, stream>>>(ybuf, zbf, gw, y2b);
  k_transpose_cvt<<<dim3(HDIM/32, INTER/32), 256, 0, stream>>>(w2, w2t, INTER, HDIM);
  k_gemm_bf16<64, 4><<<(LSEQ/64)*(HDIM/64)*4, 256, 0, stream>>>(y2b, w2t, p2, LSEQ, HDIM, INTER);
  k_reduce4<<<LSEQ*HDIM/1024, 256, 0, stream>>>(p2, out, LSEQ*HDIM);
}

// Round 17
// 133.076 us; speedup vs baseline: 1.0342x; 1.0240x over previous
//
#include <hip/hip_runtime.h>
#include <stdint.h>

#define LSEQ 512
#define HDIM 2048
#define NH 64
#define HD 64
#define INTER 4096
#define NG 4
#define NSTATE 64
#define CONVC 4608
#define PROJC 8768
#define EPS 1e-5f
#define CL 64
#define NC 8
#define NHDN (NH * HD * NSTATE)

typedef __attribute__((ext_vector_type(8))) short bf16x8;
typedef __attribute__((ext_vector_type(4))) short short4v;
typedef __attribute__((ext_vector_type(4))) float f32x4;

__device__ __forceinline__ short f2bf(float f) {
  union { float f; uint32_t u; } v; v.f = f;
  uint32_t r = v.u + 0x7FFFu + ((v.u >> 16) & 1u);
  return (short)(r >> 16);
}

// packed 2xf32 -> u32(2xbf16), RNE (same rounding as f2bf)
__device__ __forceinline__ uint32_t cvt_pk_bf16(float lo, float hi) {
  uint32_t r;
  asm("v_cvt_pk_bf16_f32 %0, %1, %2" : "=v"(r) : "v"(lo), "v"(hi));
  return r;
}

__device__ __forceinline__ float bf2f(short s) {
  union { uint32_t u; float f; } v; v.u = ((uint32_t)(uint16_t)s) << 16;
  return v.f;
}

__device__ __forceinline__ float siluf(float v) {
  return v / (1.f + expf(-v));
}

// bijective XCD-chunked swizzle (m204)
__device__ __forceinline__ int xcd_swizzle(int orig, int nwg) {
  int q = nwg >> 3, r = nwg & 7;
  int xcd = orig & 7, idx = orig >> 3;
  return (xcd < r ? xcd * (q + 1) : r * (q + 1) + (xcd - r) * q) + idx;
}

// ---------------- K1: x = h + r ; residual out ; hs = rmsnorm(x)*w -> bf16
__global__ __launch_bounds__(256) void k_add_rmsnorm(
    const float* __restrict__ hid, const float* __restrict__ res,
    const float* __restrict__ w, float* __restrict__ resid_out,
    short* __restrict__ hsb) {
  __shared__ float sred[4];
  const int row = blockIdx.x, tid = threadIdx.x;
  const float4* h4 = (const float4*)(hid + (size_t)row * HDIM);
  const float4* r4 = (const float4*)(res + (size_t)row * HDIM);
  float4* ro4 = (float4*)(resid_out + (size_t)row * HDIM);
  float4 a0 = h4[tid], b0 = r4[tid];
  float4 a1 = h4[tid + 256], b1 = r4[tid + 256];
  float4 xa, xb;
  xa.x = a0.x + b0.x; xa.y = a0.y + b0.y; xa.z = a0.z + b0.z; xa.w = a0.w + b0.w;
  xb.x = a1.x + b1.x; xb.y = a1.y + b1.y; xb.z = a1.z + b1.z; xb.w = a1.w + b1.w;
  ro4[tid] = xa; ro4[tid + 256] = xb;
  float ss = xa.x*xa.x + xa.y*xa.y + xa.z*xa.z + xa.w*xa.w
           + xb.x*xb.x + xb.y*xb.y + xb.z*xb.z + xb.w*xb.w;
  #pragma unroll
  for (int off = 32; off >= 1; off >>= 1) ss += __shfl_down(ss, off);
  if ((tid & 63) == 0) sred[tid >> 6] = ss;
  __syncthreads();
  float tot = sred[0] + sred[1] + sred[2] + sred[3];
  float rs = rsqrtf(tot / (float)HDIM + EPS);
  int e0 = tid * 4, e1 = (tid + 256) * 4;
  short4v s0, s1;
  s0.x = f2bf(xa.x * rs * w[e0+0]); s0.y = f2bf(xa.y * rs * w[e0+1]);
  s0.z = f2bf(xa.z * rs * w[e0+2]); s0.w = f2bf(xa.w * rs * w[e0+3]);
  s1.x = f2bf(xb.x * rs * w[e1+0]); s1.y = f2bf(xb.y * rs * w[e1+1]);
  s1.z = f2bf(xb.z * rs * w[e1+2]); s1.w = f2bf(xb.w * rs * w[e1+3]);
  *(short4v*)(hsb + (size_t)row * HDIM + e0) = s0;
  *(short4v*)(hsb + (size_t)row * HDIM + e1) = s1;
}

// ---------------- K2: dst[c][r] = bf16(src[r][c])   src: R x C f32
__global__ __launch_bounds__(256) void k_transpose_cvt(
    const float* __restrict__ src, short* __restrict__ dst, int R, int C) {
  __shared__ float tile[32][33];
  const int tx = threadIdx.x & 31, ty = threadIdx.x >> 5;
  const int c0 = blockIdx.x * 32, r0 = blockIdx.y * 32;
  #pragma unroll
  for (int i = 0; i < 4; ++i)
    tile[ty + i*8][tx] = src[(size_t)(r0 + ty + i*8) * C + c0 + tx];
  __syncthreads();
  #pragma unroll
  for (int i = 0; i < 4; ++i)
    dst[(size_t)(c0 + ty + i*8) * R + r0 + tx] = f2bf(tile[tx][ty + i*8]);
}

// ---------------- GEMM1: proj = hs(bf16) * w1(f32, K x N natural)
// Fused f32->bf16 B-conversion. Single-buffered lB (40KB LDS -> 4 blocks/CU).
// Epilogue routes into zbf / xbc / dtf by n-block. (R14 structure, best.)
__global__ __launch_bounds__(256) void k_gemm1(
    const short* __restrict__ A, const float* __restrict__ Bw,
    short* __restrict__ zbf, short* __restrict__ xbc,
    float* __restrict__ dtf) {
  constexpr int BM = 128, MR = 4, WROWS = 64;
  const int M = LSEQ, N = PROJC, K = HDIM;
  __shared__ short lA[2][BM * 64];
  __shared__ short lB[64 * 64];
  const int tid = threadIdx.x, lane = tid & 63, wid = tid >> 6;

  const int NMB = M / BM, NNB = N / 64;
  const int nwg = NMB * NNB;
  int wg = xcd_swizzle(blockIdx.x, nwg);
  const int mi = wg % NMB;
  const int ni = wg / NMB;
  const int m0 = mi * BM, n0 = ni * 64;
  const int wm = wid >> 1, wn = wid & 1;

  const int lrow8 = lane >> 3;
  const int cswz = ((lane & 7) ^ lrow8) * 8;

  auto stageA = [&](int buf, int kt) {
    #pragma unroll
    for (int r2 = 0; r2 < MR; ++r2) {
      int idx = r2 * 4 + wid;
      __builtin_amdgcn_global_load_lds(
          (const __attribute__((address_space(1))) int*)(A + (size_t)(m0 + idx * 8 + lrow8) * K + kt + cswz),
          (__attribute__((address_space(3))) int*)(&lA[buf][idx * 512]),
          16, 0, 0);
    }
  };

  float breg[16];
  auto loadB = [&](int kt) {
    #pragma unroll
    for (int r = 0; r < 2; ++r)
      #pragma unroll
      for (int j = 0; j < 8; ++j)
        breg[r * 8 + j] = Bw[(size_t)(kt + wid * 16 + r * 8 + j) * N + n0 + lane];
  };
  auto writeB = [&]() {
    #pragma unroll
    for (int r = 0; r < 2; ++r) {
      uint4 v;
      v.x = cvt_pk_bf16(breg[r*8+0], breg[r*8+1]);
      v.y = cvt_pk_bf16(breg[r*8+2], breg[r*8+3]);
      v.z = cvt_pk_bf16(breg[r*8+4], breg[r*8+5]);
      v.w = cvt_pk_bf16(breg[r*8+6], breg[r*8+7]);
      int ko = wid * 2 + r;
      *(uint4*)&lB[lane * 64 + ((ko ^ (lane & 7)) << 3)] = v;
    }
  };

  f32x4 acc[MR][2] = {};
  const int lrow = lane & 15, lkb = (lane >> 4) * 8;
  const int NT = K >> 6;
  loadB(0);
  stageA(0, 0);
  writeB();
  asm volatile("s_waitcnt vmcnt(0)" ::: "memory");
  asm volatile("s_waitcnt lgkmcnt(0)" ::: "memory");
  __builtin_amdgcn_s_barrier();
  for (int t = 0; t < NT; ++t) {
    int cur = t & 1;
    if (t + 1 < NT) {
      loadB((t + 1) * 64);
      stageA(cur ^ 1, (t + 1) * 64);
    }
    #pragma unroll
    for (int kk = 0; kk < 2; ++kk) {
      bf16x8 a[MR], b[2];
      #pragma unroll
      for (int m = 0; m < MR; ++m) {
        int row = wm * WROWS + m * 16 + lrow;
        int colel = (kk * 32 + lkb) ^ ((row & 7) << 3);
        a[m] = *(const bf16x8*)&lA[cur][row * 64 + colel];
      }
      #pragma unroll
      for (int n = 0; n < 2; ++n) {
        int row = wn * 32 + n * 16 + lrow;
        int colel = (kk * 32 + lkb) ^ ((row & 7) << 3);
        b[n] = *(const bf16x8*)&lB[row * 64 + colel];
      }
      #pragma unroll
      for (int m = 0; m < MR; ++m)
        #pragma unroll
        for (int n = 0; n < 2; ++n)
          acc[m][n] = __builtin_amdgcn_mfma_f32_16x16x32_bf16(a[m], b[n], acc[m][n], 0, 0, 0);
    }
    __builtin_amdgcn_s_barrier();          // all waves done reading lB
    if (t + 1 < NT) writeB();              // auto-waits B loads only (counted)
    asm volatile("s_waitcnt vmcnt(0)" ::: "memory");
    asm volatile("s_waitcnt lgkmcnt(0)" ::: "memory");
    __builtin_amdgcn_s_barrier();
  }
  // epilogue: route by n-block (uniform branch)
  #pragma unroll
  for (int m = 0; m < MR; ++m) {
    int row = m0 + wm * WROWS + m * 16 + (lane >> 4) * 4;
    #pragma unroll
    for (int n = 0; n < 2; ++n) {
      int coll = wn * 32 + n * 16 + (lane & 15);
      #pragma unroll
      for (int r = 0; r < 4; ++r) {
        float v = acc[m][n][r];
        if (ni < 64)
          zbf[(size_t)(row + r) * INTER + n0 + coll] = f2bf(v);
        else if (ni < 136)
          xbc[(size_t)(row + r) * CONVC + (n0 - INTER) + coll] = f2bf(v);
        else
          dtf[(row + r) * 64 + coll] = v;
      }
    }
  }
}

// ---------------- GEMM-bf16 (gemm2): P[zi] = A(bf16) * B(bf16, N x K)^T
// bf16 partials (summed in K=512 chunks; rounding well within tolerance).
template <int BM, int KS>
__global__ __launch_bounds__(256) void k_gemm_bf16(
    const short* __restrict__ A, const short* __restrict__ B,
    short* __restrict__ C, int M, int N, int K) {
  __shared__ short lA[2][BM * 64];
  __shared__ short lB[2][64 * 64];
  const int tid = threadIdx.x;
  const int lane = tid & 63, wid = tid >> 6;
  constexpr int MR = BM / 32;
  constexpr int WROWS = BM / 2;

  const int NMB = M / BM, NNB = N / 64;
  const int nwg = NMB * NNB * KS;
  int wg = xcd_swizzle(blockIdx.x, nwg);
  const int mi = wg % NMB;
  int rest = wg / NMB;
  const int zi = (KS > 1) ? (rest % KS) : 0;
  const int ni = (KS > 1) ? (rest / KS) : rest;
  const int m0 = mi * BM, n0 = ni * 64;
  const int wm = wid >> 1, wn = wid & 1;

  const int lrow8 = lane >> 3;
  const int cswz = ((lane & 7) ^ lrow8) * 8;

  const int Kc = K / KS;
  const int kbase = zi * Kc;
  short* Cp = C + (size_t)zi * M * N;

  auto stage = [&](int buf, int kt) {
    #pragma unroll
    for (int r2 = 0; r2 < MR; ++r2) {
      int idx = r2 * 4 + wid;
      __builtin_amdgcn_global_load_lds(
          (const __attribute__((address_space(1))) int*)(A + (size_t)(m0 + idx * 8 + lrow8) * K + kt + cswz),
          (__attribute__((address_space(3))) int*)(&lA[buf][idx * 512]),
          16, 0, 0);
    }
    #pragma unroll
    for (int r2 = 0; r2 < 2; ++r2) {
      int idx = r2 * 4 + wid;
      __builtin_amdgcn_global_load_lds(
          (const __attribute__((address_space(1))) int*)(B + (size_t)(n0 + idx * 8 + lrow8) * K + kt + cswz),
          (__attribute__((address_space(3))) int*)(&lB[buf][idx * 512]),
          16, 0, 0);
    }
  };

  f32x4 acc[MR][2] = {};
  const int lrow = lane & 15, lkb = (lane >> 4) * 8;
  const int NT = Kc >> 6;
  stage(0, kbase);
  for (int t = 0; t < NT; ++t) {
    int cur = t & 1;
    if (t + 1 < NT) {
      stage(cur ^ 1, kbase + (t + 1) * 64);
      if constexpr (MR == 2) asm volatile("s_waitcnt vmcnt(4)" ::: "memory");
      else                   asm volatile("s_waitcnt vmcnt(6)" ::: "memory");
    } else {
      asm volatile("s_waitcnt vmcnt(0)" ::: "memory");
    }
    __builtin_amdgcn_s_barrier();
    #pragma unroll
    for (int kk = 0; kk < 2; ++kk) {
      bf16x8 a[MR], b[2];
      #pragma unroll
      for (int m = 0; m < MR; ++m) {
        int row = wm * WROWS + m * 16 + lrow;
        int colel = (kk * 32 + lkb) ^ ((row & 7) << 3);
        a[m] = *(const bf16x8*)&lA[cur][row * 64 + colel];
      }
      #pragma unroll
      for (int n = 0; n < 2; ++n) {
        int row = wn * 32 + n * 16 + lrow;
        int colel = (kk * 32 + lkb) ^ ((row & 7) << 3);
        b[n] = *(const bf16x8*)&lB[cur][row * 64 + colel];
      }
      #pragma unroll
      for (int m = 0; m < MR; ++m)
        #pragma unroll
        for (int n = 0; n < 2; ++n)
          acc[m][n] = __builtin_amdgcn_mfma_f32_16x16x32_bf16(a[m], b[n], acc[m][n], 0, 0, 0);
    }
    __builtin_amdgcn_s_barrier();
  }
  #pragma unroll
  for (int m = 0; m < MR; ++m) {
    int row = m0 + wm * WROWS + m * 16 + (lane >> 4) * 4;
    int col = n0 + wn * 32 + (lane & 15);
    #pragma unroll
    for (int n = 0; n < 2; ++n)
      #pragma unroll
      for (int r = 0; r < 4; ++r)
        Cp[(size_t)(row + r) * N + col + n * 16] = f2bf(acc[m][n][r]);
  }
}

// ---------------- reduce for split-K gemm2: out = sum of 8 bf16 partials
__global__ __launch_bounds__(256) void k_reduce8(
    const short* __restrict__ p, float* __restrict__ out, int n) {
  int i = (blockIdx.x * 256 + threadIdx.x) * 4;
  float4 o = {0.f, 0.f, 0.f, 0.f};
  #pragma unroll
  for (int z = 0; z < 8; ++z) {
    short4v v = *(const short4v*)(p + (size_t)z * n + i);
    o.x += bf2f(v.x); o.y += bf2f(v.y); o.z += bf2f(v.z); o.w += bf2f(v.w);
  }
  *(float4*)(out + i) = o;
}

// ---------------- K4: causal conv1d + silu (bf16 in/out) + dt/log-dA
__global__ __launch_bounds__(256) void k_conv(
    const short* __restrict__ xbc, const float* __restrict__ dtf,
    const float* __restrict__ cw, const float* __restrict__ cb,
    const float* __restrict__ A_log, const float* __restrict__ dt_bias,
    short* __restrict__ convo, float* __restrict__ dtb,
    float* __restrict__ ldab) {
  const int l0 = blockIdx.y * 64;
  if (blockIdx.x == CONVC / 256) {          // dt block
    #pragma unroll
    for (int i = 0; i < 16; ++i) {
      int idx = threadIdx.x + i * 256;
      int l = l0 + (idx >> 6), h = idx & 63;
      float v = dtf[l * 64 + h] + dt_bias[h];
      float dt = v > 20.f ? v : log1pf(expf(v));
      float lda = dt * (-expf(A_log[h]));
      dtb[h * LSEQ + l] = dt;
      ldab[h * LSEQ + l] = lda;
    }
    return;
  }
  const int c = blockIdx.x * 256 + threadIdx.x;
  const float w0 = cw[c*4+0], w1 = cw[c*4+1], w2 = cw[c*4+2], w3 = cw[c*4+3];
  const float bias = cb[c];
  float x0 = 0.f, x1 = 0.f, x2 = 0.f;
  if (l0 > 0) {
    x0 = bf2f(xbc[(size_t)(l0-3) * CONVC + c]);
    x1 = bf2f(xbc[(size_t)(l0-2) * CONVC + c]);
    x2 = bf2f(xbc[(size_t)(l0-1) * CONVC + c]);
  }
  for (int l = l0; l < l0 + 64; ++l) {
    float x3 = bf2f(xbc[(size_t)l * CONVC + c]);
    float accv = bias + x0*w0 + x1*w1 + x2*w2 + x3*w3;
    convo[(size_t)l * CONVC + c] = f2bf(siluf(accv));
    x0 = x1; x1 = x2; x2 = x3;
  }
}

// ---------------- K5a: SSD chunk kernel — per (chunk, head), all MFMA.
__global__ __launch_bounds__(256) void k_ssd(
    const short* __restrict__ convo, const float* __restrict__ dtb,
    const float* __restrict__ ldab, const float* __restrict__ Dp,
    short* __restrict__ ybuf, float* __restrict__ hend,
    float* __restrict__ Pbuf, float* __restrict__ cdbuf) {
  __shared__ __align__(16) short Xt[64 * 72];   // [d][l]
  __shared__ __align__(16) short Bs[64 * 72];   // [l][n]
  __shared__ __align__(16) short Cs[64 * 72];   // [l][n]
  __shared__ __align__(16) short Btw[64 * 72];  // [n][l], w-folded
  __shared__ __align__(16) short Ms[64 * 72];   // [i][j]
  __shared__ float s_s[64], s_dt[64], s_w[64];
  const int c = blockIdx.x, head = blockIdx.y;
  const int g = head >> 4;
  const int tid = threadIdx.x, lane = tid & 63, wid = tid >> 6;
  const int l0 = c * CL;
  const short* xbase = convo + (size_t)l0 * CONVC + head * HD;
  const short* Bbase = convo + (size_t)l0 * CONVC + INTER + g * NSTATE;
  const short* Cbase = convo + (size_t)l0 * CONVC + INTER + NG * NSTATE + g * NSTATE;

  if (tid < 64) {
    float ps = ldab[head * LSEQ + l0 + tid];
    #pragma unroll
    for (int o = 1; o < 64; o <<= 1) {
      float u = __shfl_up(ps, o);
      if (tid >= o) ps += u;
    }
    float dtv = dtb[head * LSEQ + l0 + tid];
    s_s[tid] = ps;
    s_dt[tid] = dtv;
    float s63 = __shfl(ps, 63);
    s_w[tid] = __expf(s63 - ps) * dtv;
    cdbuf[head * LSEQ + l0 + tid] = __expf(ps);
    if (tid == 63) Pbuf[c * NH + head] = __expf(ps);
  }
  #pragma unroll
  for (int rep = 0; rep < 4; ++rep) {
    int l = (tid >> 4) + rep * 16;
    int d = (tid & 15) * 4;
    size_t roff = (size_t)l * CONVC;
    short4v xv = *(const short4v*)(xbase + roff + d);
    Xt[(d + 0) * 72 + l] = xv.x;
    Xt[(d + 1) * 72 + l] = xv.y;
    Xt[(d + 2) * 72 + l] = xv.z;
    Xt[(d + 3) * 72 + l] = xv.w;
    *(short4v*)&Bs[l * 72 + d] = *(const short4v*)(Bbase + roff + d);
    *(short4v*)&Cs[l * 72 + d] = *(const short4v*)(Cbase + roff + d);
  }
  __syncthreads();
  #pragma unroll
  for (int rep = 0; rep < 16; ++rep) {
    int idx = rep * 256 + tid;
    int l = idx >> 6, n = idx & 63;
    Btw[n * 72 + l] = f2bf(bf2f(Bs[l * 72 + n]) * s_w[l]);
  }
  __syncthreads();
  const int lrow = lane & 15, lkb = (lane >> 4) * 8;
  f32x4 sacc[4] = {};
  f32x4 hacc[4] = {};
  #pragma unroll
  for (int kk = 0; kk < 2; ++kk) {
    bf16x8 ac = *(const bf16x8*)&Cs[(wid * 16 + lrow) * 72 + kk * 32 + lkb];
    bf16x8 ax = *(const bf16x8*)&Xt[(wid * 16 + lrow) * 72 + kk * 32 + lkb];
    #pragma unroll
    for (int t4 = 0; t4 < 4; ++t4) {
      bf16x8 bb = *(const bf16x8*)&Bs[(t4 * 16 + lrow) * 72 + kk * 32 + lkb];
      bf16x8 bw = *(const bf16x8*)&Btw[(t4 * 16 + lrow) * 72 + kk * 32 + lkb];
      sacc[t4] = __builtin_amdgcn_mfma_f32_16x16x32_bf16(ac, bb, sacc[t4], 0, 0, 0);
      hacc[t4] = __builtin_amdgcn_mfma_f32_16x16x32_bf16(ax, bw, hacc[t4], 0, 0, 0);
    }
  }
  float* hb = hend + ((size_t)c * NH + head) * (HD * NSTATE);
  #pragma unroll
  for (int t4 = 0; t4 < 4; ++t4) {
    int j = t4 * 16 + lrow;
    float sj = s_s[j], dtj = s_dt[j];
    #pragma unroll
    for (int r = 0; r < 4; ++r) {
      int i = wid * 16 + (lane >> 4) * 4 + r;
      float m = (j <= i) ? __expf(s_s[i] - sj) * dtj * sacc[t4][r] : 0.f;
      Ms[i * 72 + j] = f2bf(m);
      hb[i * NSTATE + j] = hacc[t4][r];
    }
  }
  __syncthreads();
  f32x4 yacc[4] = {};
  #pragma unroll
  for (int kk = 0; kk < 2; ++kk) {
    bf16x8 am = *(const bf16x8*)&Ms[(wid * 16 + lrow) * 72 + kk * 32 + lkb];
    #pragma unroll
    for (int t4 = 0; t4 < 4; ++t4) {
      bf16x8 bx = *(const bf16x8*)&Xt[(t4 * 16 + lrow) * 72 + kk * 32 + lkb];
      yacc[t4] = __builtin_amdgcn_mfma_f32_16x16x32_bf16(am, bx, yacc[t4], 0, 0, 0);
    }
  }
  const float Dv = Dp[head];
  #pragma unroll
  for (int t4 = 0; t4 < 4; ++t4) {
    int d = t4 * 16 + lrow;
    #pragma unroll
    for (int r = 0; r < 4; ++r) {
      int i = wid * 16 + (lane >> 4) * 4 + r;
      float xv = bf2f(Xt[d * 72 + i]);
      ybuf[(size_t)(l0 + i) * INTER + head * HD + d] = f2bf(yacc[t4][r] + xv * Dv);
    }
  }
}

// ---------------- K5b: combine chunk states
__global__ __launch_bounds__(256) void k_scan_combine(
    const float* __restrict__ hend, const float* __restrict__ Pbuf,
    float* __restrict__ hinbuf) {
  const int e = blockIdx.x * 256 + threadIdx.x;
  const int head = e >> 12;
  float h = 0.f;
  #pragma unroll
  for (int c = 1; c < NC; ++c) {
    h = Pbuf[(c - 1) * NH + head] * h + hend[(size_t)(c - 1) * NHDN + e];
    hinbuf[(size_t)c * NHDN + e] = h;
  }
}

// ---------------- K5c: y[l] += cd[l] * (C_l . h_in(c))   (ybuf bf16 RMW)
__global__ __launch_bounds__(256) void k_scan_fixup(
    const short* __restrict__ convo, const float* __restrict__ hinbuf,
    const float* __restrict__ cdbuf, short* __restrict__ ybuf) {
  __shared__ float sh[NSTATE][HD + 1];
  __shared__ float sc[CL][NSTATE];
  __shared__ float scd[CL];
  const int bid = blockIdx.x;
  const int c = (bid >> 6) + 1, head = bid & 63, g = head >> 4;
  const int t = threadIdx.x;
  #pragma unroll
  for (int i = 0; i < 16; ++i) {
    int idx = t + i * 256;
    int d = idx >> 6, n = idx & 63;
    sh[n][d] = hinbuf[(size_t)c * NHDN + head * (HD * NSTATE) + idx];
  }
  #pragma unroll
  for (int i = 0; i < 16; ++i) {
    int idx = t + i * 256;
    int ll = idx >> 6, n = idx & 63;
    sc[ll][n] = bf2f(convo[(size_t)(c * CL + ll) * CONVC + INTER + NG * NSTATE + g * NSTATE + n]);
  }
  if (t < CL) scd[t] = cdbuf[head * LSEQ + c * CL + t];
  __syncthreads();
  const int d = t & 63, w = t >> 6;
  #pragma unroll
  for (int i = 0; i < 4; ++i) {
    int l0 = i * 16 + w * 4;
    float a0 = 0.f, a1 = 0.f, a2 = 0.f, a3 = 0.f;
    for (int n = 0; n < NSTATE; ++n) {
      float hv = sh[n][d];
      a0 += hv * sc[l0 + 0][n];
      a1 += hv * sc[l0 + 1][n];
      a2 += hv * sc[l0 + 2][n];
      a3 += hv * sc[l0 + 3][n];
    }
    size_t base = (size_t)(c * CL + l0) * INTER + head * HD + d;
    ybuf[base + 0 * INTER] = f2bf(bf2f(ybuf[base + 0 * INTER]) + scd[l0 + 0] * a0);
    ybuf[base + 1 * INTER] = f2bf(bf2f(ybuf[base + 1 * INTER]) + scd[l0 + 1] * a1);
    ybuf[base + 2 * INTER] = f2bf(bf2f(ybuf[base + 2 * INTER]) + scd[l0 + 2] * a2);
    ybuf[base + 3 * INTER] = f2bf(bf2f(ybuf[base + 3 * INTER]) + scd[l0 + 3] * a3);
  }
}

// ---------------- K6: y2 = rmsnorm(y * silu(z)) * gn_w -> bf16 (y,z bf16)
__global__ __launch_bounds__(256) void k_gated_norm(
    const short* __restrict__ ybuf, const short* __restrict__ zbf,
    const float* __restrict__ gw, short* __restrict__ y2b) {
  __shared__ float sred[4];
  const int row = blockIdx.x, tid = threadIdx.x;
  const short4v* y4 = (const short4v*)(ybuf + (size_t)row * INTER);
  const short4v* z4 = (const short4v*)(zbf + (size_t)row * INTER);
  float g[16];
  float ss = 0.f;
  #pragma unroll
  for (int i = 0; i < 4; ++i) {
    short4v y = y4[tid + i * 256];
    short4v z = z4[tid + i * 256];
    float g0 = bf2f(y.x) * siluf(bf2f(z.x)), g1 = bf2f(y.y) * siluf(bf2f(z.y));
    float g2 = bf2f(y.z) * siluf(bf2f(z.z)), g3 = bf2f(y.w) * siluf(bf2f(z.w));
    g[i*4+0] = g0; g[i*4+1] = g1; g[i*4+2] = g2; g[i*4+3] = g3;
    ss += g0*g0 + g1*g1 + g2*g2 + g3*g3;
  }
  #pragma unroll
  for (int off = 32; off >= 1; off >>= 1) ss += __shfl_down(ss, off);
  if ((tid & 63) == 0) sred[tid >> 6] = ss;
  __syncthreads();
  float tot = sred[0] + sred[1] + sred[2] + sred[3];
  float rs = rsqrtf(tot / (float)INTER + EPS);
  #pragma unroll
  for (int i = 0; i < 4; ++i) {
    int e = (tid + i * 256) * 4;
    short4v s;
    s.x = f2bf(g[i*4+0] * rs * gw[e+0]);
    s.y = f2bf(g[i*4+1] * rs * gw[e+1]);
    s.z = f2bf(g[i*4+2] * rs * gw[e+2]);
    s.w = f2bf(g[i*4+3] * rs * gw[e+3]);
    *(short4v*)(y2b + (size_t)row * INTER + e) = s;
  }
}

extern "C" void kernel_launch(void* const* d_in, const int* in_sizes, int n_in,
                              void* d_out, int out_size, void* d_ws, size_t ws_size,
                              hipStream_t stream) {
  const float* hid     = (const float*)d_in[0];
  const float* res     = (const float*)d_in[1];
  const float* norm_w  = (const float*)d_in[2];
  const float* w1      = (const float*)d_in[3];   // H x PROJ (K x N)
  const float* cw      = (const float*)d_in[4];   // CONV x 4
  const float* cb      = (const float*)d_in[5];
  const float* A_log   = (const float*)d_in[6];
  const float* dt_bias = (const float*)d_in[7];
  const float* Dp      = (const float*)d_in[8];
  const float* gw      = (const float*)d_in[9];
  const float* w2      = (const float*)d_in[10];  // INTER x H (K x N)

  float* out = (float*)d_out;
  float* resid_out = out + (size_t)LSEQ * HDIM;

  char* ws = (char*)d_ws;
  short* hsb  = (short*)(ws);                    // 512x2048 bf16   (2 MB)
  // [2097152, 38010880): 35.9 MB window, SEQUENTIAL lifetimes:
  //   1) hend/hinbuf/Pbuf/cdbuf — ssd/combine
  //   2) p2 (8x512x2048 bf16, 16.8MB) — gemm2 partials (after combine/fixup)
  float* hend   = (float*)(ws + 2097152);        // 8 MB
  short* p2     = (short*)(ws + 2097152);        // 16.8 MB (bf16 partials)
  float* hinbuf = (float*)(ws + 10485760);       // 8 MB
  float* Pbuf   = (float*)(ws + 18874368);
  float* cdbuf  = (float*)(ws + 18876416);       // 64x512 f32, head-major
  short* zbf  = (short*)(ws + 38010880);         // 512x4096 bf16   (4.2 MB)
  short* xbc  = (short*)(ws + 42205184);         // 512x4608 bf16   (4.7 MB)
  float* dtf  = (float*)(ws + 46923776);         // 512x64 f32
  short* convo= (short*)(ws + 55967744);         // 512x4608 bf16   (4.7 MB)
  float* dtb  = (float*)(ws + 65404928);         // 64x512 f32, head-major
  float* ldab = (float*)(ws + 65536000);         // 64x512 f32, head-major (log dA)
  short* ybuf = (short*)(ws + 65667072);         // 512x4096 bf16   (4.2 MB)
  short* y2b  = (short*)(ws + 74055680);         // 512x4096 bf16   (4.2 MB)
  short* w2t  = (short*)(ws + 78249984);         // 2048x4096 bf16  (16.8 MB)

  k_add_rmsnorm<<<LSEQ, 256, 0, stream>>>(hid, res, norm_w, resid_out, hsb);
  k_gemm1<<<(LSEQ/128)*(PROJC/64), 256, 0, stream>>>(hsb, w1, zbf, xbc, dtf);
  k_conv<<<dim3(CONVC/256 + 1, NC), 256, 0, stream>>>(xbc, dtf, cw, cb, A_log, dt_bias, convo, dtb, ldab);
  k_ssd<<<dim3(NC, NH), 256, 0, stream>>>(convo, dtb, ldab, Dp, ybuf, hend, Pbuf, cdbuf);
  k_scan_combine<<<NHDN/256, 256, 0, stream>>>(hend, Pbuf, hinbuf);
  k_scan_fixup<<<(NC-1)*NH, 256, 0, stream>>>(convo, hinbuf, cdbuf, ybuf);
  k_gated_norm<<<LSEQ, 256, 0, stream>>>(ybuf, zbf, gw, y2b);
  k_transpose_cvt<<<dim3(HDIM/32, INTER/32), 256, 0, stream>>>(w2, w2t, INTER, HDIM);
  k_gemm_bf16<64, 8><<<(LSEQ/64)*(HDIM/64)*8, 256, 0, stream>>>(y2b, w2t, p2, LSEQ, HDIM, INTER);
  k_reduce8<<<LSEQ*HDIM/1024, 256, 0, stream>>>(p2, out, LSEQ*HDIM);
}

// Round 18
// 129.564 us; speedup vs baseline: 1.0622x; 1.0271x over previous
//
#include <hip/hip_runtime.h>
#include <stdint.h>

#define LSEQ 512
#define HDIM 2048
#define NH 64
#define HD 64
#define INTER 4096
#define NG 4
#define NSTATE 64
#define CONVC 4608
#define PROJC 8768
#define EPS 1e-5f
#define CL 64
#define NC 8
#define NHDN (NH * HD * NSTATE)

typedef __attribute__((ext_vector_type(8))) short bf16x8;
typedef __attribute__((ext_vector_type(4))) short short4v;
typedef __attribute__((ext_vector_type(4))) float f32x4;

__device__ __forceinline__ short f2bf(float f) {
  union { float f; uint32_t u; } v; v.f = f;
  uint32_t r = v.u + 0x7FFFu + ((v.u >> 16) & 1u);
  return (short)(r >> 16);
}

// packed 2xf32 -> u32(2xbf16), RNE (same rounding as f2bf)
__device__ __forceinline__ uint32_t cvt_pk_bf16(float lo, float hi) {
  uint32_t r;
  asm("v_cvt_pk_bf16_f32 %0, %1, %2" : "=v"(r) : "v"(lo), "v"(hi));
  return r;
}

__device__ __forceinline__ float bf2f(short s) {
  union { uint32_t u; float f; } v; v.u = ((uint32_t)(uint16_t)s) << 16;
  return v.f;
}

__device__ __forceinline__ float siluf(float v) {
  return v / (1.f + expf(-v));
}

// bijective XCD-chunked swizzle (m204)
__device__ __forceinline__ int xcd_swizzle(int orig, int nwg) {
  int q = nwg >> 3, r = nwg & 7;
  int xcd = orig & 7, idx = orig >> 3;
  return (xcd < r ? xcd * (q + 1) : r * (q + 1) + (xcd - r) * q) + idx;
}

// ---------------- K1: x = h + r ; residual out ; hs = rmsnorm(x)*w -> bf16
__global__ __launch_bounds__(256) void k_add_rmsnorm(
    const float* __restrict__ hid, const float* __restrict__ res,
    const float* __restrict__ w, float* __restrict__ resid_out,
    short* __restrict__ hsb) {
  __shared__ float sred[4];
  const int row = blockIdx.x, tid = threadIdx.x;
  const float4* h4 = (const float4*)(hid + (size_t)row * HDIM);
  const float4* r4 = (const float4*)(res + (size_t)row * HDIM);
  float4* ro4 = (float4*)(resid_out + (size_t)row * HDIM);
  float4 a0 = h4[tid], b0 = r4[tid];
  float4 a1 = h4[tid + 256], b1 = r4[tid + 256];
  float4 xa, xb;
  xa.x = a0.x + b0.x; xa.y = a0.y + b0.y; xa.z = a0.z + b0.z; xa.w = a0.w + b0.w;
  xb.x = a1.x + b1.x; xb.y = a1.y + b1.y; xb.z = a1.z + b1.z; xb.w = a1.w + b1.w;
  ro4[tid] = xa; ro4[tid + 256] = xb;
  float ss = xa.x*xa.x + xa.y*xa.y + xa.z*xa.z + xa.w*xa.w
           + xb.x*xb.x + xb.y*xb.y + xb.z*xb.z + xb.w*xb.w;
  #pragma unroll
  for (int off = 32; off >= 1; off >>= 1) ss += __shfl_down(ss, off);
  if ((tid & 63) == 0) sred[tid >> 6] = ss;
  __syncthreads();
  float tot = sred[0] + sred[1] + sred[2] + sred[3];
  float rs = rsqrtf(tot / (float)HDIM + EPS);
  int e0 = tid * 4, e1 = (tid + 256) * 4;
  short4v s0, s1;
  s0.x = f2bf(xa.x * rs * w[e0+0]); s0.y = f2bf(xa.y * rs * w[e0+1]);
  s0.z = f2bf(xa.z * rs * w[e0+2]); s0.w = f2bf(xa.w * rs * w[e0+3]);
  s1.x = f2bf(xb.x * rs * w[e1+0]); s1.y = f2bf(xb.y * rs * w[e1+1]);
  s1.z = f2bf(xb.z * rs * w[e1+2]); s1.w = f2bf(xb.w * rs * w[e1+3]);
  *(short4v*)(hsb + (size_t)row * HDIM + e0) = s0;
  *(short4v*)(hsb + (size_t)row * HDIM + e1) = s1;
}

// ---------------- K2: dst[c][r] = bf16(src[r][c])   src: R x C f32
__global__ __launch_bounds__(256) void k_transpose_cvt(
    const float* __restrict__ src, short* __restrict__ dst, int R, int C) {
  __shared__ float tile[32][33];
  const int tx = threadIdx.x & 31, ty = threadIdx.x >> 5;
  const int c0 = blockIdx.x * 32, r0 = blockIdx.y * 32;
  #pragma unroll
  for (int i = 0; i < 4; ++i)
    tile[ty + i*8][tx] = src[(size_t)(r0 + ty + i*8) * C + c0 + tx];
  __syncthreads();
  #pragma unroll
  for (int i = 0; i < 4; ++i)
    dst[(size_t)(c0 + ty + i*8) * R + r0 + tx] = f2bf(tile[tx][ty + i*8]);
}

// ---------------- GEMM1: proj = hs(bf16) * w1(f32, K x N natural)
// Fused f32->bf16 B-conversion. Single-buffered lB (40KB LDS -> 4 blocks/CU).
// Epilogue routes into zbf / xbc / dtf by n-block. (R14 structure, best.)
__global__ __launch_bounds__(256) void k_gemm1(
    const short* __restrict__ A, const float* __restrict__ Bw,
    short* __restrict__ zbf, short* __restrict__ xbc,
    float* __restrict__ dtf) {
  constexpr int BM = 128, MR = 4, WROWS = 64;
  const int M = LSEQ, N = PROJC, K = HDIM;
  __shared__ short lA[2][BM * 64];
  __shared__ short lB[64 * 64];
  const int tid = threadIdx.x, lane = tid & 63, wid = tid >> 6;

  const int NMB = M / BM, NNB = N / 64;
  const int nwg = NMB * NNB;
  int wg = xcd_swizzle(blockIdx.x, nwg);
  const int mi = wg % NMB;
  const int ni = wg / NMB;
  const int m0 = mi * BM, n0 = ni * 64;
  const int wm = wid >> 1, wn = wid & 1;

  const int lrow8 = lane >> 3;
  const int cswz = ((lane & 7) ^ lrow8) * 8;

  auto stageA = [&](int buf, int kt) {
    #pragma unroll
    for (int r2 = 0; r2 < MR; ++r2) {
      int idx = r2 * 4 + wid;
      __builtin_amdgcn_global_load_lds(
          (const __attribute__((address_space(1))) int*)(A + (size_t)(m0 + idx * 8 + lrow8) * K + kt + cswz),
          (__attribute__((address_space(3))) int*)(&lA[buf][idx * 512]),
          16, 0, 0);
    }
  };

  float breg[16];
  auto loadB = [&](int kt) {
    #pragma unroll
    for (int r = 0; r < 2; ++r)
      #pragma unroll
      for (int j = 0; j < 8; ++j)
        breg[r * 8 + j] = Bw[(size_t)(kt + wid * 16 + r * 8 + j) * N + n0 + lane];
  };
  auto writeB = [&]() {
    #pragma unroll
    for (int r = 0; r < 2; ++r) {
      uint4 v;
      v.x = cvt_pk_bf16(breg[r*8+0], breg[r*8+1]);
      v.y = cvt_pk_bf16(breg[r*8+2], breg[r*8+3]);
      v.z = cvt_pk_bf16(breg[r*8+4], breg[r*8+5]);
      v.w = cvt_pk_bf16(breg[r*8+6], breg[r*8+7]);
      int ko = wid * 2 + r;
      *(uint4*)&lB[lane * 64 + ((ko ^ (lane & 7)) << 3)] = v;
    }
  };

  f32x4 acc[MR][2] = {};
  const int lrow = lane & 15, lkb = (lane >> 4) * 8;
  const int NT = K >> 6;
  loadB(0);
  stageA(0, 0);
  writeB();
  asm volatile("s_waitcnt vmcnt(0)" ::: "memory");
  asm volatile("s_waitcnt lgkmcnt(0)" ::: "memory");
  __builtin_amdgcn_s_barrier();
  for (int t = 0; t < NT; ++t) {
    int cur = t & 1;
    if (t + 1 < NT) {
      loadB((t + 1) * 64);
      stageA(cur ^ 1, (t + 1) * 64);
    }
    #pragma unroll
    for (int kk = 0; kk < 2; ++kk) {
      bf16x8 a[MR], b[2];
      #pragma unroll
      for (int m = 0; m < MR; ++m) {
        int row = wm * WROWS + m * 16 + lrow;
        int colel = (kk * 32 + lkb) ^ ((row & 7) << 3);
        a[m] = *(const bf16x8*)&lA[cur][row * 64 + colel];
      }
      #pragma unroll
      for (int n = 0; n < 2; ++n) {
        int row = wn * 32 + n * 16 + lrow;
        int colel = (kk * 32 + lkb) ^ ((row & 7) << 3);
        b[n] = *(const bf16x8*)&lB[row * 64 + colel];
      }
      #pragma unroll
      for (int m = 0; m < MR; ++m)
        #pragma unroll
        for (int n = 0; n < 2; ++n)
          acc[m][n] = __builtin_amdgcn_mfma_f32_16x16x32_bf16(a[m], b[n], acc[m][n], 0, 0, 0);
    }
    __builtin_amdgcn_s_barrier();          // all waves done reading lB
    if (t + 1 < NT) writeB();              // auto-waits B loads only (counted)
    asm volatile("s_waitcnt vmcnt(0)" ::: "memory");
    asm volatile("s_waitcnt lgkmcnt(0)" ::: "memory");
    __builtin_amdgcn_s_barrier();
  }
  // epilogue: route by n-block (uniform branch)
  #pragma unroll
  for (int m = 0; m < MR; ++m) {
    int row = m0 + wm * WROWS + m * 16 + (lane >> 4) * 4;
    #pragma unroll
    for (int n = 0; n < 2; ++n) {
      int coll = wn * 32 + n * 16 + (lane & 15);
      #pragma unroll
      for (int r = 0; r < 4; ++r) {
        float v = acc[m][n][r];
        if (ni < 64)
          zbf[(size_t)(row + r) * INTER + n0 + coll] = f2bf(v);
        else if (ni < 136)
          xbc[(size_t)(row + r) * CONVC + (n0 - INTER) + coll] = f2bf(v);
        else
          dtf[(row + r) * 64 + coll] = v;
      }
    }
  }
}

// ---------------- GEMM-bf16 (gemm2): P[zi] = A(bf16) * B(bf16, N x K)^T
// bf16 partials at KS=4 (R14 schedule, halved partial traffic).
template <int BM, int KS>
__global__ __launch_bounds__(256) void k_gemm_bf16(
    const short* __restrict__ A, const short* __restrict__ B,
    short* __restrict__ C, int M, int N, int K) {
  __shared__ short lA[2][BM * 64];
  __shared__ short lB[2][64 * 64];
  const int tid = threadIdx.x;
  const int lane = tid & 63, wid = tid >> 6;
  constexpr int MR = BM / 32;
  constexpr int WROWS = BM / 2;

  const int NMB = M / BM, NNB = N / 64;
  const int nwg = NMB * NNB * KS;
  int wg = xcd_swizzle(blockIdx.x, nwg);
  const int mi = wg % NMB;
  int rest = wg / NMB;
  const int zi = (KS > 1) ? (rest % KS) : 0;
  const int ni = (KS > 1) ? (rest / KS) : rest;
  const int m0 = mi * BM, n0 = ni * 64;
  const int wm = wid >> 1, wn = wid & 1;

  const int lrow8 = lane >> 3;
  const int cswz = ((lane & 7) ^ lrow8) * 8;

  const int Kc = K / KS;
  const int kbase = zi * Kc;
  short* Cp = C + (size_t)zi * M * N;

  auto stage = [&](int buf, int kt) {
    #pragma unroll
    for (int r2 = 0; r2 < MR; ++r2) {
      int idx = r2 * 4 + wid;
      __builtin_amdgcn_global_load_lds(
          (const __attribute__((address_space(1))) int*)(A + (size_t)(m0 + idx * 8 + lrow8) * K + kt + cswz),
          (__attribute__((address_space(3))) int*)(&lA[buf][idx * 512]),
          16, 0, 0);
    }
    #pragma unroll
    for (int r2 = 0; r2 < 2; ++r2) {
      int idx = r2 * 4 + wid;
      __builtin_amdgcn_global_load_lds(
          (const __attribute__((address_space(1))) int*)(B + (size_t)(n0 + idx * 8 + lrow8) * K + kt + cswz),
          (__attribute__((address_space(3))) int*)(&lB[buf][idx * 512]),
          16, 0, 0);
    }
  };

  f32x4 acc[MR][2] = {};
  const int lrow = lane & 15, lkb = (lane >> 4) * 8;
  const int NT = Kc >> 6;
  stage(0, kbase);
  for (int t = 0; t < NT; ++t) {
    int cur = t & 1;
    if (t + 1 < NT) {
      stage(cur ^ 1, kbase + (t + 1) * 64);
      if constexpr (MR == 2) asm volatile("s_waitcnt vmcnt(4)" ::: "memory");
      else                   asm volatile("s_waitcnt vmcnt(6)" ::: "memory");
    } else {
      asm volatile("s_waitcnt vmcnt(0)" ::: "memory");
    }
    __builtin_amdgcn_s_barrier();
    #pragma unroll
    for (int kk = 0; kk < 2; ++kk) {
      bf16x8 a[MR], b[2];
      #pragma unroll
      for (int m = 0; m < MR; ++m) {
        int row = wm * WROWS + m * 16 + lrow;
        int colel = (kk * 32 + lkb) ^ ((row & 7) << 3);
        a[m] = *(const bf16x8*)&lA[cur][row * 64 + colel];
      }
      #pragma unroll
      for (int n = 0; n < 2; ++n) {
        int row = wn * 32 + n * 16 + lrow;
        int colel = (kk * 32 + lkb) ^ ((row & 7) << 3);
        b[n] = *(const bf16x8*)&lB[cur][row * 64 + colel];
      }
      #pragma unroll
      for (int m = 0; m < MR; ++m)
        #pragma unroll
        for (int n = 0; n < 2; ++n)
          acc[m][n] = __builtin_amdgcn_mfma_f32_16x16x32_bf16(a[m], b[n], acc[m][n], 0, 0, 0);
    }
    __builtin_amdgcn_s_barrier();
  }
  #pragma unroll
  for (int m = 0; m < MR; ++m) {
    int row = m0 + wm * WROWS + m * 16 + (lane >> 4) * 4;
    int col = n0 + wn * 32 + (lane & 15);
    #pragma unroll
    for (int n = 0; n < 2; ++n)
      #pragma unroll
      for (int r = 0; r < 4; ++r)
        Cp[(size_t)(row + r) * N + col + n * 16] = f2bf(acc[m][n][r]);
  }
}

// ---------------- reduce for split-K gemm2: out = sum of 4 bf16 partials
__global__ __launch_bounds__(256) void k_reduce4(
    const short* __restrict__ p, float* __restrict__ out, int n) {
  int i = (blockIdx.x * 256 + threadIdx.x) * 4;
  float4 o = {0.f, 0.f, 0.f, 0.f};
  #pragma unroll
  for (int z = 0; z < 4; ++z) {
    short4v v = *(const short4v*)(p + (size_t)z * n + i);
    o.x += bf2f(v.x); o.y += bf2f(v.y); o.z += bf2f(v.z); o.w += bf2f(v.w);
  }
  *(float4*)(out + i) = o;
}

// ---------------- K4: causal conv1d + silu (bf16 in/out) + dt/log-dA
__global__ __launch_bounds__(256) void k_conv(
    const short* __restrict__ xbc, const float* __restrict__ dtf,
    const float* __restrict__ cw, const float* __restrict__ cb,
    const float* __restrict__ A_log, const float* __restrict__ dt_bias,
    short* __restrict__ convo, float* __restrict__ dtb,
    float* __restrict__ ldab) {
  const int l0 = blockIdx.y * 64;
  if (blockIdx.x == CONVC / 256) {          // dt block
    #pragma unroll
    for (int i = 0; i < 16; ++i) {
      int idx = threadIdx.x + i * 256;
      int l = l0 + (idx >> 6), h = idx & 63;
      float v = dtf[l * 64 + h] + dt_bias[h];
      float dt = v > 20.f ? v : log1pf(expf(v));
      float lda = dt * (-expf(A_log[h]));
      dtb[h * LSEQ + l] = dt;
      ldab[h * LSEQ + l] = lda;
    }
    return;
  }
  const int c = blockIdx.x * 256 + threadIdx.x;
  const float w0 = cw[c*4+0], w1 = cw[c*4+1], w2 = cw[c*4+2], w3 = cw[c*4+3];
  const float bias = cb[c];
  float x0 = 0.f, x1 = 0.f, x2 = 0.f;
  if (l0 > 0) {
    x0 = bf2f(xbc[(size_t)(l0-3) * CONVC + c]);
    x1 = bf2f(xbc[(size_t)(l0-2) * CONVC + c]);
    x2 = bf2f(xbc[(size_t)(l0-1) * CONVC + c]);
  }
  for (int l = l0; l < l0 + 64; ++l) {
    float x3 = bf2f(xbc[(size_t)l * CONVC + c]);
    float accv = bias + x0*w0 + x1*w1 + x2*w2 + x3*w3;
    convo[(size_t)l * CONVC + c] = f2bf(siluf(accv));
    x0 = x1; x1 = x2; x2 = x3;
  }
}

// ---------------- K5a: SSD chunk kernel — per (chunk, head), all MFMA.
__global__ __launch_bounds__(256) void k_ssd(
    const short* __restrict__ convo, const float* __restrict__ dtb,
    const float* __restrict__ ldab, const float* __restrict__ Dp,
    short* __restrict__ ybuf, float* __restrict__ hend,
    float* __restrict__ Pbuf, float* __restrict__ cdbuf) {
  __shared__ __align__(16) short Xt[64 * 72];   // [d][l]
  __shared__ __align__(16) short Bs[64 * 72];   // [l][n]
  __shared__ __align__(16) short Cs[64 * 72];   // [l][n]
  __shared__ __align__(16) short Btw[64 * 72];  // [n][l], w-folded
  __shared__ __align__(16) short Ms[64 * 72];   // [i][j]
  __shared__ float s_s[64], s_dt[64], s_w[64];
  const int c = blockIdx.x, head = blockIdx.y;
  const int g = head >> 4;
  const int tid = threadIdx.x, lane = tid & 63, wid = tid >> 6;
  const int l0 = c * CL;
  const short* xbase = convo + (size_t)l0 * CONVC + head * HD;
  const short* Bbase = convo + (size_t)l0 * CONVC + INTER + g * NSTATE;
  const short* Cbase = convo + (size_t)l0 * CONVC + INTER + NG * NSTATE + g * NSTATE;

  if (tid < 64) {
    float ps = ldab[head * LSEQ + l0 + tid];
    #pragma unroll
    for (int o = 1; o < 64; o <<= 1) {
      float u = __shfl_up(ps, o);
      if (tid >= o) ps += u;
    }
    float dtv = dtb[head * LSEQ + l0 + tid];
    s_s[tid] = ps;
    s_dt[tid] = dtv;
    float s63 = __shfl(ps, 63);
    s_w[tid] = __expf(s63 - ps) * dtv;
    cdbuf[head * LSEQ + l0 + tid] = __expf(ps);
    if (tid == 63) Pbuf[c * NH + head] = __expf(ps);
  }
  #pragma unroll
  for (int rep = 0; rep < 4; ++rep) {
    int l = (tid >> 4) + rep * 16;
    int d = (tid & 15) * 4;
    size_t roff = (size_t)l * CONVC;
    short4v xv = *(const short4v*)(xbase + roff + d);
    Xt[(d + 0) * 72 + l] = xv.x;
    Xt[(d + 1) * 72 + l] = xv.y;
    Xt[(d + 2) * 72 + l] = xv.z;
    Xt[(d + 3) * 72 + l] = xv.w;
    *(short4v*)&Bs[l * 72 + d] = *(const short4v*)(Bbase + roff + d);
    *(short4v*)&Cs[l * 72 + d] = *(const short4v*)(Cbase + roff + d);
  }
  __syncthreads();
  #pragma unroll
  for (int rep = 0; rep < 16; ++rep) {
    int idx = rep * 256 + tid;
    int l = idx >> 6, n = idx & 63;
    Btw[n * 72 + l] = f2bf(bf2f(Bs[l * 72 + n]) * s_w[l]);
  }
  __syncthreads();
  const int lrow = lane & 15, lkb = (lane >> 4) * 8;
  f32x4 sacc[4] = {};
  f32x4 hacc[4] = {};
  #pragma unroll
  for (int kk = 0; kk < 2; ++kk) {
    bf16x8 ac = *(const bf16x8*)&Cs[(wid * 16 + lrow) * 72 + kk * 32 + lkb];
    bf16x8 ax = *(const bf16x8*)&Xt[(wid * 16 + lrow) * 72 + kk * 32 + lkb];
    #pragma unroll
    for (int t4 = 0; t4 < 4; ++t4) {
      bf16x8 bb = *(const bf16x8*)&Bs[(t4 * 16 + lrow) * 72 + kk * 32 + lkb];
      bf16x8 bw = *(const bf16x8*)&Btw[(t4 * 16 + lrow) * 72 + kk * 32 + lkb];
      sacc[t4] = __builtin_amdgcn_mfma_f32_16x16x32_bf16(ac, bb, sacc[t4], 0, 0, 0);
      hacc[t4] = __builtin_amdgcn_mfma_f32_16x16x32_bf16(ax, bw, hacc[t4], 0, 0, 0);
    }
  }
  float* hb = hend + ((size_t)c * NH + head) * (HD * NSTATE);
  #pragma unroll
  for (int t4 = 0; t4 < 4; ++t4) {
    int j = t4 * 16 + lrow;
    float sj = s_s[j], dtj = s_dt[j];
    #pragma unroll
    for (int r = 0; r < 4; ++r) {
      int i = wid * 16 + (lane >> 4) * 4 + r;
      float m = (j <= i) ? __expf(s_s[i] - sj) * dtj * sacc[t4][r] : 0.f;
      Ms[i * 72 + j] = f2bf(m);
      hb[i * NSTATE + j] = hacc[t4][r];
    }
  }
  __syncthreads();
  f32x4 yacc[4] = {};
  #pragma unroll
  for (int kk = 0; kk < 2; ++kk) {
    bf16x8 am = *(const bf16x8*)&Ms[(wid * 16 + lrow) * 72 + kk * 32 + lkb];
    #pragma unroll
    for (int t4 = 0; t4 < 4; ++t4) {
      bf16x8 bx = *(const bf16x8*)&Xt[(t4 * 16 + lrow) * 72 + kk * 32 + lkb];
      yacc[t4] = __builtin_amdgcn_mfma_f32_16x16x32_bf16(am, bx, yacc[t4], 0, 0, 0);
    }
  }
  const float Dv = Dp[head];
  #pragma unroll
  for (int t4 = 0; t4 < 4; ++t4) {
    int d = t4 * 16 + lrow;
    #pragma unroll
    for (int r = 0; r < 4; ++r) {
      int i = wid * 16 + (lane >> 4) * 4 + r;
      float xv = bf2f(Xt[d * 72 + i]);
      ybuf[(size_t)(l0 + i) * INTER + head * HD + d] = f2bf(yacc[t4][r] + xv * Dv);
    }
  }
}

// ---------------- K5b: combine chunk states
__global__ __launch_bounds__(256) void k_scan_combine(
    const float* __restrict__ hend, const float* __restrict__ Pbuf,
    float* __restrict__ hinbuf) {
  const int e = blockIdx.x * 256 + threadIdx.x;
  const int head = e >> 12;
  float h = 0.f;
  #pragma unroll
  for (int c = 1; c < NC; ++c) {
    h = Pbuf[(c - 1) * NH + head] * h + hend[(size_t)(c - 1) * NHDN + e];
    hinbuf[(size_t)c * NHDN + e] = h;
  }
}

// ---------------- K5c: y[l] += cd[l] * (C_l . h_in(c))   (ybuf bf16 RMW)
__global__ __launch_bounds__(256) void k_scan_fixup(
    const short* __restrict__ convo, const float* __restrict__ hinbuf,
    const float* __restrict__ cdbuf, short* __restrict__ ybuf) {
  __shared__ float sh[NSTATE][HD + 1];
  __shared__ float sc[CL][NSTATE];
  __shared__ float scd[CL];
  const int bid = blockIdx.x;
  const int c = (bid >> 6) + 1, head = bid & 63, g = head >> 4;
  const int t = threadIdx.x;
  #pragma unroll
  for (int i = 0; i < 16; ++i) {
    int idx = t + i * 256;
    int d = idx >> 6, n = idx & 63;
    sh[n][d] = hinbuf[(size_t)c * NHDN + head * (HD * NSTATE) + idx];
  }
  #pragma unroll
  for (int i = 0; i < 16; ++i) {
    int idx = t + i * 256;
    int ll = idx >> 6, n = idx & 63;
    sc[ll][n] = bf2f(convo[(size_t)(c * CL + ll) * CONVC + INTER + NG * NSTATE + g * NSTATE + n]);
  }
  if (t < CL) scd[t] = cdbuf[head * LSEQ + c * CL + t];
  __syncthreads();
  const int d = t & 63, w = t >> 6;
  #pragma unroll
  for (int i = 0; i < 4; ++i) {
    int l0 = i * 16 + w * 4;
    float a0 = 0.f, a1 = 0.f, a2 = 0.f, a3 = 0.f;
    for (int n = 0; n < NSTATE; ++n) {
      float hv = sh[n][d];
      a0 += hv * sc[l0 + 0][n];
      a1 += hv * sc[l0 + 1][n];
      a2 += hv * sc[l0 + 2][n];
      a3 += hv * sc[l0 + 3][n];
    }
    size_t base = (size_t)(c * CL + l0) * INTER + head * HD + d;
    ybuf[base + 0 * INTER] = f2bf(bf2f(ybuf[base + 0 * INTER]) + scd[l0 + 0] * a0);
    ybuf[base + 1 * INTER] = f2bf(bf2f(ybuf[base + 1 * INTER]) + scd[l0 + 1] * a1);
    ybuf[base + 2 * INTER] = f2bf(bf2f(ybuf[base + 2 * INTER]) + scd[l0 + 2] * a2);
    ybuf[base + 3 * INTER] = f2bf(bf2f(ybuf[base + 3 * INTER]) + scd[l0 + 3] * a3);
  }
}

// ---------------- K6: y2 = rmsnorm(y * silu(z)) * gn_w -> bf16 (y,z bf16)
__global__ __launch_bounds__(256) void k_gated_norm(
    const short* __restrict__ ybuf, const short* __restrict__ zbf,
    const float* __restrict__ gw, short* __restrict__ y2b) {
  __shared__ float sred[4];
  const int row = blockIdx.x, tid = threadIdx.x;
  const short4v* y4 = (const short4v*)(ybuf + (size_t)row * INTER);
  const short4v* z4 = (const short4v*)(zbf + (size_t)row * INTER);
  float g[16];
  float ss = 0.f;
  #pragma unroll
  for (int i = 0; i < 4; ++i) {
    short4v y = y4[tid + i * 256];
    short4v z = z4[tid + i * 256];
    float g0 = bf2f(y.x) * siluf(bf2f(z.x)), g1 = bf2f(y.y) * siluf(bf2f(z.y));
    float g2 = bf2f(y.z) * siluf(bf2f(z.z)), g3 = bf2f(y.w) * siluf(bf2f(z.w));
    g[i*4+0] = g0; g[i*4+1] = g1; g[i*4+2] = g2; g[i*4+3] = g3;
    ss += g0*g0 + g1*g1 + g2*g2 + g3*g3;
  }
  #pragma unroll
  for (int off = 32; off >= 1; off >>= 1) ss += __shfl_down(ss, off);
  if ((tid & 63) == 0) sred[tid >> 6] = ss;
  __syncthreads();
  float tot = sred[0] + sred[1] + sred[2] + sred[3];
  float rs = rsqrtf(tot / (float)INTER + EPS);
  #pragma unroll
  for (int i = 0; i < 4; ++i) {
    int e = (tid + i * 256) * 4;
    short4v s;
    s.x = f2bf(g[i*4+0] * rs * gw[e+0]);
    s.y = f2bf(g[i*4+1] * rs * gw[e+1]);
    s.z = f2bf(g[i*4+2] * rs * gw[e+2]);
    s.w = f2bf(g[i*4+3] * rs * gw[e+3]);
    *(short4v*)(y2b + (size_t)row * INTER + e) = s;
  }
}

extern "C" void kernel_launch(void* const* d_in, const int* in_sizes, int n_in,
                              void* d_out, int out_size, void* d_ws, size_t ws_size,
                              hipStream_t stream) {
  const float* hid     = (const float*)d_in[0];
  const float* res     = (const float*)d_in[1];
  const float* norm_w  = (const float*)d_in[2];
  const float* w1      = (const float*)d_in[3];   // H x PROJ (K x N)
  const float* cw      = (const float*)d_in[4];   // CONV x 4
  const float* cb      = (const float*)d_in[5];
  const float* A_log   = (const float*)d_in[6];
  const float* dt_bias = (const float*)d_in[7];
  const float* Dp      = (const float*)d_in[8];
  const float* gw      = (const float*)d_in[9];
  const float* w2      = (const float*)d_in[10];  // INTER x H (K x N)

  float* out = (float*)d_out;
  float* resid_out = out + (size_t)LSEQ * HDIM;

  char* ws = (char*)d_ws;
  short* hsb  = (short*)(ws);                    // 512x2048 bf16   (2 MB)
  // [2097152, 38010880): 35.9 MB window, SEQUENTIAL lifetimes:
  //   1) hend/hinbuf/Pbuf/cdbuf — ssd/combine
  //   2) p2 (4x512x2048 bf16, 8.4MB) — gemm2 partials (after combine/fixup)
  float* hend   = (float*)(ws + 2097152);        // 8 MB
  short* p2     = (short*)(ws + 2097152);        // 8.4 MB (bf16 partials)
  float* hinbuf = (float*)(ws + 10485760);       // 8 MB
  float* Pbuf   = (float*)(ws + 18874368);
  float* cdbuf  = (float*)(ws + 18876416);       // 64x512 f32, head-major
  short* zbf  = (short*)(ws + 38010880);         // 512x4096 bf16   (4.2 MB)
  short* xbc  = (short*)(ws + 42205184);         // 512x4608 bf16   (4.7 MB)
  float* dtf  = (float*)(ws + 46923776);         // 512x64 f32
  short* convo= (short*)(ws + 55967744);         // 512x4608 bf16   (4.7 MB)
  float* dtb  = (float*)(ws + 65404928);         // 64x512 f32, head-major
  float* ldab = (float*)(ws + 65536000);         // 64x512 f32, head-major (log dA)
  short* ybuf = (short*)(ws + 65667072);         // 512x4096 bf16   (4.2 MB)
  short* y2b  = (short*)(ws + 74055680);         // 512x4096 bf16   (4.2 MB)
  short* w2t  = (short*)(ws + 78249984);         // 2048x4096 bf16  (16.8 MB)

  k_add_rmsnorm<<<LSEQ, 256, 0, stream>>>(hid, res, norm_w, resid_out, hsb);
  k_gemm1<<<(LSEQ/128)*(PROJC/64), 256, 0, stream>>>(hsb, w1, zbf, xbc, dtf);
  k_conv<<<dim3(CONVC/256 + 1, NC), 256, 0, stream>>>(xbc, dtf, cw, cb, A_log, dt_bias, convo, dtb, ldab);
  k_ssd<<<dim3(NC, NH), 256, 0, stream>>>(convo, dtb, ldab, Dp, ybuf, hend, Pbuf, cdbuf);
  k_scan_combine<<<NHDN/256, 256, 0, stream>>>(hend, Pbuf, hinbuf);
  k_scan_fixup<<<(NC-1)*NH, 256, 0, stream>>>(convo, hinbuf, cdbuf, ybuf);
  k_gated_norm<<<LSEQ, 256, 0, stream>>>(ybuf, zbf, gw, y2b);
  k_transpose_cvt<<<dim3(HDIM/32, INTER/32), 256, 0, stream>>>(w2, w2t, INTER, HDIM);
  k_gemm_bf16<64, 4><<<(LSEQ/64)*(HDIM/64)*4, 256, 0, stream>>>(y2b, w2t, p2, LSEQ, HDIM, INTER);
  k_reduce4<<<LSEQ*HDIM/1024, 256, 0, stream>>>(p2, out, LSEQ*HDIM);
}

// Round 19
// 120.372 us; speedup vs baseline: 1.1433x; 1.0764x over previous
//
#include <hip/hip_runtime.h>
#include <stdint.h>

#define LSEQ 512
#define HDIM 2048
#define NH 64
#define HD 64
#define INTER 4096
#define NG 4
#define NSTATE 64
#define CONVC 4608
#define PROJC 8768
#define EPS 1e-5f
#define CL 64
#define NC 8
#define NHDN (NH * HD * NSTATE)

typedef __attribute__((ext_vector_type(8))) short bf16x8;
typedef __attribute__((ext_vector_type(4))) short short4v;
typedef __attribute__((ext_vector_type(4))) float f32x4;

__device__ __forceinline__ short f2bf(float f) {
  union { float f; uint32_t u; } v; v.f = f;
  uint32_t r = v.u + 0x7FFFu + ((v.u >> 16) & 1u);
  return (short)(r >> 16);
}

// packed 2xf32 -> u32(2xbf16), RNE (same rounding as f2bf)
__device__ __forceinline__ uint32_t cvt_pk_bf16(float lo, float hi) {
  uint32_t r;
  asm("v_cvt_pk_bf16_f32 %0, %1, %2" : "=v"(r) : "v"(lo), "v"(hi));
  return r;
}

__device__ __forceinline__ float bf2f(short s) {
  union { uint32_t u; float f; } v; v.u = ((uint32_t)(uint16_t)s) << 16;
  return v.f;
}

__device__ __forceinline__ float siluf(float v) {
  return v / (1.f + expf(-v));
}

// bijective XCD-chunked swizzle (m204)
__device__ __forceinline__ int xcd_swizzle(int orig, int nwg) {
  int q = nwg >> 3, r = nwg & 7;
  int xcd = orig & 7, idx = orig >> 3;
  return (xcd < r ? xcd * (q + 1) : r * (q + 1) + (xcd - r) * q) + idx;
}

// ---------------- K1: x = h + r ; residual out ; hs = rmsnorm(x)*w -> bf16
__global__ __launch_bounds__(256) void k_add_rmsnorm(
    const float* __restrict__ hid, const float* __restrict__ res,
    const float* __restrict__ w, float* __restrict__ resid_out,
    short* __restrict__ hsb) {
  __shared__ float sred[4];
  const int row = blockIdx.x, tid = threadIdx.x;
  const float4* h4 = (const float4*)(hid + (size_t)row * HDIM);
  const float4* r4 = (const float4*)(res + (size_t)row * HDIM);
  float4* ro4 = (float4*)(resid_out + (size_t)row * HDIM);
  float4 a0 = h4[tid], b0 = r4[tid];
  float4 a1 = h4[tid + 256], b1 = r4[tid + 256];
  float4 xa, xb;
  xa.x = a0.x + b0.x; xa.y = a0.y + b0.y; xa.z = a0.z + b0.z; xa.w = a0.w + b0.w;
  xb.x = a1.x + b1.x; xb.y = a1.y + b1.y; xb.z = a1.z + b1.z; xb.w = a1.w + b1.w;
  ro4[tid] = xa; ro4[tid + 256] = xb;
  float ss = xa.x*xa.x + xa.y*xa.y + xa.z*xa.z + xa.w*xa.w
           + xb.x*xb.x + xb.y*xb.y + xb.z*xb.z + xb.w*xb.w;
  #pragma unroll
  for (int off = 32; off >= 1; off >>= 1) ss += __shfl_down(ss, off);
  if ((tid & 63) == 0) sred[tid >> 6] = ss;
  __syncthreads();
  float tot = sred[0] + sred[1] + sred[2] + sred[3];
  float rs = rsqrtf(tot / (float)HDIM + EPS);
  int e0 = tid * 4, e1 = (tid + 256) * 4;
  short4v s0, s1;
  s0.x = f2bf(xa.x * rs * w[e0+0]); s0.y = f2bf(xa.y * rs * w[e0+1]);
  s0.z = f2bf(xa.z * rs * w[e0+2]); s0.w = f2bf(xa.w * rs * w[e0+3]);
  s1.x = f2bf(xb.x * rs * w[e1+0]); s1.y = f2bf(xb.y * rs * w[e1+1]);
  s1.z = f2bf(xb.z * rs * w[e1+2]); s1.w = f2bf(xb.w * rs * w[e1+3]);
  *(short4v*)(hsb + (size_t)row * HDIM + e0) = s0;
  *(short4v*)(hsb + (size_t)row * HDIM + e1) = s1;
}

// ---------------- GEMM1 + fused w2 transpose (heterogeneous grid):
//  blocks [0, 548): proj = hs(bf16) * w1(f32 natural), fused B-conversion,
//    single-buffer lB (40KB LDS), routing epilogue (R14/R18 structure).
//  blocks [548, 548+512): w2 (INTER x HDIM f32) -> w2t (HDIM x INTER bf16),
//    16 grid-strided 32x32 tiles each; overlaps gemm1's latency stalls.
__global__ __launch_bounds__(256) void k_gemm1(
    const short* __restrict__ A, const float* __restrict__ Bw,
    short* __restrict__ zbf, short* __restrict__ xbc,
    float* __restrict__ dtf,
    const float* __restrict__ w2src, short* __restrict__ w2dst) {
  constexpr int BM = 128, MR = 4, WROWS = 64;
  const int M = LSEQ, N = PROJC, K = HDIM;
  __shared__ short lA[2][BM * 64];
  __shared__ short lB[64 * 64];
  const int tid = threadIdx.x, lane = tid & 63, wid = tid >> 6;

  const int NMB = M / BM, NNB = N / 64;
  const int nwg = NMB * NNB;                     // 548 gemm blocks

  if (blockIdx.x >= nwg) {                       // ---- transpose path ----
    float (*tile)[33] = (float(*)[33])lA;        // 4.2KB aliased into lA
    const int tb = blockIdx.x - nwg;             // 0..511
    const int tx = tid & 31, ty = tid >> 5;
    for (int i = 0; i < 16; ++i) {
      int t = tb + i * 512;                      // 8192 tiles = 64 x 128
      int c0 = (t & 63) * 32;                    // over HDIM
      int r0 = (t >> 6) * 32;                    // over INTER
      #pragma unroll
      for (int j = 0; j < 4; ++j)
        tile[ty + j*8][tx] = w2src[(size_t)(r0 + ty + j*8) * HDIM + c0 + tx];
      __syncthreads();
      #pragma unroll
      for (int j = 0; j < 4; ++j)
        w2dst[(size_t)(c0 + ty + j*8) * INTER + r0 + tx] = f2bf(tile[tx][ty + j*8]);
      __syncthreads();
    }
    return;
  }

  int wg = xcd_swizzle(blockIdx.x, nwg);
  const int mi = wg % NMB;
  const int ni = wg / NMB;
  const int m0 = mi * BM, n0 = ni * 64;
  const int wm = wid >> 1, wn = wid & 1;

  const int lrow8 = lane >> 3;
  const int cswz = ((lane & 7) ^ lrow8) * 8;

  auto stageA = [&](int buf, int kt) {
    #pragma unroll
    for (int r2 = 0; r2 < MR; ++r2) {
      int idx = r2 * 4 + wid;
      __builtin_amdgcn_global_load_lds(
          (const __attribute__((address_space(1))) int*)(A + (size_t)(m0 + idx * 8 + lrow8) * K + kt + cswz),
          (__attribute__((address_space(3))) int*)(&lA[buf][idx * 512]),
          16, 0, 0);
    }
  };

  float breg[16];
  auto loadB = [&](int kt) {
    #pragma unroll
    for (int r = 0; r < 2; ++r)
      #pragma unroll
      for (int j = 0; j < 8; ++j)
        breg[r * 8 + j] = Bw[(size_t)(kt + wid * 16 + r * 8 + j) * N + n0 + lane];
  };
  auto writeB = [&]() {
    #pragma unroll
    for (int r = 0; r < 2; ++r) {
      uint4 v;
      v.x = cvt_pk_bf16(breg[r*8+0], breg[r*8+1]);
      v.y = cvt_pk_bf16(breg[r*8+2], breg[r*8+3]);
      v.z = cvt_pk_bf16(breg[r*8+4], breg[r*8+5]);
      v.w = cvt_pk_bf16(breg[r*8+6], breg[r*8+7]);
      int ko = wid * 2 + r;
      *(uint4*)&lB[lane * 64 + ((ko ^ (lane & 7)) << 3)] = v;
    }
  };

  f32x4 acc[MR][2] = {};
  const int lrow = lane & 15, lkb = (lane >> 4) * 8;
  const int NT = K >> 6;
  loadB(0);
  stageA(0, 0);
  writeB();
  asm volatile("s_waitcnt vmcnt(0)" ::: "memory");
  asm volatile("s_waitcnt lgkmcnt(0)" ::: "memory");
  __builtin_amdgcn_s_barrier();
  for (int t = 0; t < NT; ++t) {
    int cur = t & 1;
    if (t + 1 < NT) {
      loadB((t + 1) * 64);
      stageA(cur ^ 1, (t + 1) * 64);
    }
    #pragma unroll
    for (int kk = 0; kk < 2; ++kk) {
      bf16x8 a[MR], b[2];
      #pragma unroll
      for (int m = 0; m < MR; ++m) {
        int row = wm * WROWS + m * 16 + lrow;
        int colel = (kk * 32 + lkb) ^ ((row & 7) << 3);
        a[m] = *(const bf16x8*)&lA[cur][row * 64 + colel];
      }
      #pragma unroll
      for (int n = 0; n < 2; ++n) {
        int row = wn * 32 + n * 16 + lrow;
        int colel = (kk * 32 + lkb) ^ ((row & 7) << 3);
        b[n] = *(const bf16x8*)&lB[row * 64 + colel];
      }
      #pragma unroll
      for (int m = 0; m < MR; ++m)
        #pragma unroll
        for (int n = 0; n < 2; ++n)
          acc[m][n] = __builtin_amdgcn_mfma_f32_16x16x32_bf16(a[m], b[n], acc[m][n], 0, 0, 0);
    }
    __builtin_amdgcn_s_barrier();          // all waves done reading lB
    if (t + 1 < NT) writeB();              // auto-waits B loads only (counted)
    asm volatile("s_waitcnt vmcnt(0)" ::: "memory");
    asm volatile("s_waitcnt lgkmcnt(0)" ::: "memory");
    __builtin_amdgcn_s_barrier();
  }
  // epilogue: route by n-block (uniform branch)
  #pragma unroll
  for (int m = 0; m < MR; ++m) {
    int row = m0 + wm * WROWS + m * 16 + (lane >> 4) * 4;
    #pragma unroll
    for (int n = 0; n < 2; ++n) {
      int coll = wn * 32 + n * 16 + (lane & 15);
      #pragma unroll
      for (int r = 0; r < 4; ++r) {
        float v = acc[m][n][r];
        if (ni < 64)
          zbf[(size_t)(row + r) * INTER + n0 + coll] = f2bf(v);
        else if (ni < 136)
          xbc[(size_t)(row + r) * CONVC + (n0 - INTER) + coll] = f2bf(v);
        else
          dtf[(row + r) * 64 + coll] = v;
      }
    }
  }
}

// ---------------- GEMM-bf16 (gemm2): P[zi] = A(bf16) * B(bf16, N x K)^T
// bf16 partials at KS=4 (R18 schedule).
template <int BM, int KS>
__global__ __launch_bounds__(256) void k_gemm_bf16(
    const short* __restrict__ A, const short* __restrict__ B,
    short* __restrict__ C, int M, int N, int K) {
  __shared__ short lA[2][BM * 64];
  __shared__ short lB[2][64 * 64];
  const int tid = threadIdx.x;
  const int lane = tid & 63, wid = tid >> 6;
  constexpr int MR = BM / 32;
  constexpr int WROWS = BM / 2;

  const int NMB = M / BM, NNB = N / 64;
  const int nwg = NMB * NNB * KS;
  int wg = xcd_swizzle(blockIdx.x, nwg);
  const int mi = wg % NMB;
  int rest = wg / NMB;
  const int zi = (KS > 1) ? (rest % KS) : 0;
  const int ni = (KS > 1) ? (rest / KS) : rest;
  const int m0 = mi * BM, n0 = ni * 64;
  const int wm = wid >> 1, wn = wid & 1;

  const int lrow8 = lane >> 3;
  const int cswz = ((lane & 7) ^ lrow8) * 8;

  const int Kc = K / KS;
  const int kbase = zi * Kc;
  short* Cp = C + (size_t)zi * M * N;

  auto stage = [&](int buf, int kt) {
    #pragma unroll
    for (int r2 = 0; r2 < MR; ++r2) {
      int idx = r2 * 4 + wid;
      __builtin_amdgcn_global_load_lds(
          (const __attribute__((address_space(1))) int*)(A + (size_t)(m0 + idx * 8 + lrow8) * K + kt + cswz),
          (__attribute__((address_space(3))) int*)(&lA[buf][idx * 512]),
          16, 0, 0);
    }
    #pragma unroll
    for (int r2 = 0; r2 < 2; ++r2) {
      int idx = r2 * 4 + wid;
      __builtin_amdgcn_global_load_lds(
          (const __attribute__((address_space(1))) int*)(B + (size_t)(n0 + idx * 8 + lrow8) * K + kt + cswz),
          (__attribute__((address_space(3))) int*)(&lB[buf][idx * 512]),
          16, 0, 0);
    }
  };

  f32x4 acc[MR][2] = {};
  const int lrow = lane & 15, lkb = (lane >> 4) * 8;
  const int NT = Kc >> 6;
  stage(0, kbase);
  for (int t = 0; t < NT; ++t) {
    int cur = t & 1;
    if (t + 1 < NT) {
      stage(cur ^ 1, kbase + (t + 1) * 64);
      if constexpr (MR == 2) asm volatile("s_waitcnt vmcnt(4)" ::: "memory");
      else                   asm volatile("s_waitcnt vmcnt(6)" ::: "memory");
    } else {
      asm volatile("s_waitcnt vmcnt(0)" ::: "memory");
    }
    __builtin_amdgcn_s_barrier();
    #pragma unroll
    for (int kk = 0; kk < 2; ++kk) {
      bf16x8 a[MR], b[2];
      #pragma unroll
      for (int m = 0; m < MR; ++m) {
        int row = wm * WROWS + m * 16 + lrow;
        int colel = (kk * 32 + lkb) ^ ((row & 7) << 3);
        a[m] = *(const bf16x8*)&lA[cur][row * 64 + colel];
      }
      #pragma unroll
      for (int n = 0; n < 2; ++n) {
        int row = wn * 32 + n * 16 + lrow;
        int colel = (kk * 32 + lkb) ^ ((row & 7) << 3);
        b[n] = *(const bf16x8*)&lB[cur][row * 64 + colel];
      }
      #pragma unroll
      for (int m = 0; m < MR; ++m)
        #pragma unroll
        for (int n = 0; n < 2; ++n)
          acc[m][n] = __builtin_amdgcn_mfma_f32_16x16x32_bf16(a[m], b[n], acc[m][n], 0, 0, 0);
    }
    __builtin_amdgcn_s_barrier();
  }
  #pragma unroll
  for (int m = 0; m < MR; ++m) {
    int row = m0 + wm * WROWS + m * 16 + (lane >> 4) * 4;
    int col = n0 + wn * 32 + (lane & 15);
    #pragma unroll
    for (int n = 0; n < 2; ++n)
      #pragma unroll
      for (int r = 0; r < 4; ++r)
        Cp[(size_t)(row + r) * N + col + n * 16] = f2bf(acc[m][n][r]);
  }
}

// ---------------- reduce for split-K gemm2: out = sum of 4 bf16 partials
__global__ __launch_bounds__(256) void k_reduce4(
    const short* __restrict__ p, float* __restrict__ out, int n) {
  int i = (blockIdx.x * 256 + threadIdx.x) * 4;
  float4 o = {0.f, 0.f, 0.f, 0.f};
  #pragma unroll
  for (int z = 0; z < 4; ++z) {
    short4v v = *(const short4v*)(p + (size_t)z * n + i);
    o.x += bf2f(v.x); o.y += bf2f(v.y); o.z += bf2f(v.z); o.w += bf2f(v.w);
  }
  *(float4*)(out + i) = o;
}

// ---------------- K4: causal conv1d + silu (bf16 in/out) + dt/log-dA
__global__ __launch_bounds__(256) void k_conv(
    const short* __restrict__ xbc, const float* __restrict__ dtf,
    const float* __restrict__ cw, const float* __restrict__ cb,
    const float* __restrict__ A_log, const float* __restrict__ dt_bias,
    short* __restrict__ convo, float* __restrict__ dtb,
    float* __restrict__ ldab) {
  const int l0 = blockIdx.y * 64;
  if (blockIdx.x == CONVC / 256) {          // dt block
    #pragma unroll
    for (int i = 0; i < 16; ++i) {
      int idx = threadIdx.x + i * 256;
      int l = l0 + (idx >> 6), h = idx & 63;
      float v = dtf[l * 64 + h] + dt_bias[h];
      float dt = v > 20.f ? v : log1pf(expf(v));
      float lda = dt * (-expf(A_log[h]));
      dtb[h * LSEQ + l] = dt;
      ldab[h * LSEQ + l] = lda;
    }
    return;
  }
  const int c = blockIdx.x * 256 + threadIdx.x;
  const float w0 = cw[c*4+0], w1 = cw[c*4+1], w2 = cw[c*4+2], w3 = cw[c*4+3];
  const float bias = cb[c];
  float x0 = 0.f, x1 = 0.f, x2 = 0.f;
  if (l0 > 0) {
    x0 = bf2f(xbc[(size_t)(l0-3) * CONVC + c]);
    x1 = bf2f(xbc[(size_t)(l0-2) * CONVC + c]);
    x2 = bf2f(xbc[(size_t)(l0-1) * CONVC + c]);
  }
  for (int l = l0; l < l0 + 64; ++l) {
    float x3 = bf2f(xbc[(size_t)l * CONVC + c]);
    float accv = bias + x0*w0 + x1*w1 + x2*w2 + x3*w3;
    convo[(size_t)l * CONVC + c] = f2bf(siluf(accv));
    x0 = x1; x1 = x2; x2 = x3;
  }
}

// ---------------- K5a: SSD chunk kernel — per (chunk, head), all MFMA.
__global__ __launch_bounds__(256) void k_ssd(
    const short* __restrict__ convo, const float* __restrict__ dtb,
    const float* __restrict__ ldab, const float* __restrict__ Dp,
    short* __restrict__ ybuf, float* __restrict__ hend,
    float* __restrict__ Pbuf, float* __restrict__ cdbuf) {
  __shared__ __align__(16) short Xt[64 * 72];   // [d][l]
  __shared__ __align__(16) short Bs[64 * 72];   // [l][n]
  __shared__ __align__(16) short Cs[64 * 72];   // [l][n]
  __shared__ __align__(16) short Btw[64 * 72];  // [n][l], w-folded
  __shared__ __align__(16) short Ms[64 * 72];   // [i][j]
  __shared__ float s_s[64], s_dt[64], s_w[64];
  const int c = blockIdx.x, head = blockIdx.y;
  const int g = head >> 4;
  const int tid = threadIdx.x, lane = tid & 63, wid = tid >> 6;
  const int l0 = c * CL;
  const short* xbase = convo + (size_t)l0 * CONVC + head * HD;
  const short* Bbase = convo + (size_t)l0 * CONVC + INTER + g * NSTATE;
  const short* Cbase = convo + (size_t)l0 * CONVC + INTER + NG * NSTATE + g * NSTATE;

  if (tid < 64) {
    float ps = ldab[head * LSEQ + l0 + tid];
    #pragma unroll
    for (int o = 1; o < 64; o <<= 1) {
      float u = __shfl_up(ps, o);
      if (tid >= o) ps += u;
    }
    float dtv = dtb[head * LSEQ + l0 + tid];
    s_s[tid] = ps;
    s_dt[tid] = dtv;
    float s63 = __shfl(ps, 63);
    s_w[tid] = __expf(s63 - ps) * dtv;
    cdbuf[head * LSEQ + l0 + tid] = __expf(ps);
    if (tid == 63) Pbuf[c * NH + head] = __expf(ps);
  }
  #pragma unroll
  for (int rep = 0; rep < 4; ++rep) {
    int l = (tid >> 4) + rep * 16;
    int d = (tid & 15) * 4;
    size_t roff = (size_t)l * CONVC;
    short4v xv = *(const short4v*)(xbase + roff + d);
    Xt[(d + 0) * 72 + l] = xv.x;
    Xt[(d + 1) * 72 + l] = xv.y;
    Xt[(d + 2) * 72 + l] = xv.z;
    Xt[(d + 3) * 72 + l] = xv.w;
    *(short4v*)&Bs[l * 72 + d] = *(const short4v*)(Bbase + roff + d);
    *(short4v*)&Cs[l * 72 + d] = *(const short4v*)(Cbase + roff + d);
  }
  __syncthreads();
  #pragma unroll
  for (int rep = 0; rep < 16; ++rep) {
    int idx = rep * 256 + tid;
    int l = idx >> 6, n = idx & 63;
    Btw[n * 72 + l] = f2bf(bf2f(Bs[l * 72 + n]) * s_w[l]);
  }
  __syncthreads();
  const int lrow = lane & 15, lkb = (lane >> 4) * 8;
  f32x4 sacc[4] = {};
  f32x4 hacc[4] = {};
  #pragma unroll
  for (int kk = 0; kk < 2; ++kk) {
    bf16x8 ac = *(const bf16x8*)&Cs[(wid * 16 + lrow) * 72 + kk * 32 + lkb];
    bf16x8 ax = *(const bf16x8*)&Xt[(wid * 16 + lrow) * 72 + kk * 32 + lkb];
    #pragma unroll
    for (int t4 = 0; t4 < 4; ++t4) {
      bf16x8 bb = *(const bf16x8*)&Bs[(t4 * 16 + lrow) * 72 + kk * 32 + lkb];
      bf16x8 bw = *(const bf16x8*)&Btw[(t4 * 16 + lrow) * 72 + kk * 32 + lkb];
      sacc[t4] = __builtin_amdgcn_mfma_f32_16x16x32_bf16(ac, bb, sacc[t4], 0, 0, 0);
      hacc[t4] = __builtin_amdgcn_mfma_f32_16x16x32_bf16(ax, bw, hacc[t4], 0, 0, 0);
    }
  }
  float* hb = hend + ((size_t)c * NH + head) * (HD * NSTATE);
  #pragma unroll
  for (int t4 = 0; t4 < 4; ++t4) {
    int j = t4 * 16 + lrow;
    float sj = s_s[j], dtj = s_dt[j];
    #pragma unroll
    for (int r = 0; r < 4; ++r) {
      int i = wid * 16 + (lane >> 4) * 4 + r;
      float m = (j <= i) ? __expf(s_s[i] - sj) * dtj * sacc[t4][r] : 0.f;
      Ms[i * 72 + j] = f2bf(m);
      hb[i * NSTATE + j] = hacc[t4][r];
    }
  }
  __syncthreads();
  f32x4 yacc[4] = {};
  #pragma unroll
  for (int kk = 0; kk < 2; ++kk) {
    bf16x8 am = *(const bf16x8*)&Ms[(wid * 16 + lrow) * 72 + kk * 32 + lkb];
    #pragma unroll
    for (int t4 = 0; t4 < 4; ++t4) {
      bf16x8 bx = *(const bf16x8*)&Xt[(t4 * 16 + lrow) * 72 + kk * 32 + lkb];
      yacc[t4] = __builtin_amdgcn_mfma_f32_16x16x32_bf16(am, bx, yacc[t4], 0, 0, 0);
    }
  }
  const float Dv = Dp[head];
  #pragma unroll
  for (int t4 = 0; t4 < 4; ++t4) {
    int d = t4 * 16 + lrow;
    #pragma unroll
    for (int r = 0; r < 4; ++r) {
      int i = wid * 16 + (lane >> 4) * 4 + r;
      float xv = bf2f(Xt[d * 72 + i]);
      ybuf[(size_t)(l0 + i) * INTER + head * HD + d] = f2bf(yacc[t4][r] + xv * Dv);
    }
  }
}

// ---------------- K5b: combine chunk states
__global__ __launch_bounds__(256) void k_scan_combine(
    const float* __restrict__ hend, const float* __restrict__ Pbuf,
    float* __restrict__ hinbuf) {
  const int e = blockIdx.x * 256 + threadIdx.x;
  const int head = e >> 12;
  float h = 0.f;
  #pragma unroll
  for (int c = 1; c < NC; ++c) {
    h = Pbuf[(c - 1) * NH + head] * h + hend[(size_t)(c - 1) * NHDN + e];
    hinbuf[(size_t)c * NHDN + e] = h;
  }
}

// ---------------- K5c: y[l] += cd[l] * (C_l . h_in(c))   (ybuf bf16 RMW)
__global__ __launch_bounds__(256) void k_scan_fixup(
    const short* __restrict__ convo, const float* __restrict__ hinbuf,
    const float* __restrict__ cdbuf, short* __restrict__ ybuf) {
  __shared__ float sh[NSTATE][HD + 1];
  __shared__ float sc[CL][NSTATE];
  __shared__ float scd[CL];
  const int bid = blockIdx.x;
  const int c = (bid >> 6) + 1, head = bid & 63, g = head >> 4;
  const int t = threadIdx.x;
  #pragma unroll
  for (int i = 0; i < 16; ++i) {
    int idx = t + i * 256;
    int d = idx >> 6, n = idx & 63;
    sh[n][d] = hinbuf[(size_t)c * NHDN + head * (HD * NSTATE) + idx];
  }
  #pragma unroll
  for (int i = 0; i < 16; ++i) {
    int idx = t + i * 256;
    int ll = idx >> 6, n = idx & 63;
    sc[ll][n] = bf2f(convo[(size_t)(c * CL + ll) * CONVC + INTER + NG * NSTATE + g * NSTATE + n]);
  }
  if (t < CL) scd[t] = cdbuf[head * LSEQ + c * CL + t];
  __syncthreads();
  const int d = t & 63, w = t >> 6;
  #pragma unroll
  for (int i = 0; i < 4; ++i) {
    int l0 = i * 16 + w * 4;
    float a0 = 0.f, a1 = 0.f, a2 = 0.f, a3 = 0.f;
    for (int n = 0; n < NSTATE; ++n) {
      float hv = sh[n][d];
      a0 += hv * sc[l0 + 0][n];
      a1 += hv * sc[l0 + 1][n];
      a2 += hv * sc[l0 + 2][n];
      a3 += hv * sc[l0 + 3][n];
    }
    size_t base = (size_t)(c * CL + l0) * INTER + head * HD + d;
    ybuf[base + 0 * INTER] = f2bf(bf2f(ybuf[base + 0 * INTER]) + scd[l0 + 0] * a0);
    ybuf[base + 1 * INTER] = f2bf(bf2f(ybuf[base + 1 * INTER]) + scd[l0 + 1] * a1);
    ybuf[base + 2 * INTER] = f2bf(bf2f(ybuf[base + 2 * INTER]) + scd[l0 + 2] * a2);
    ybuf[base + 3 * INTER] = f2bf(bf2f(ybuf[base + 3 * INTER]) + scd[l0 + 3] * a3);
  }
}

// ---------------- K6: y2 = rmsnorm(y * silu(z)) * gn_w -> bf16 (y,z bf16)
__global__ __launch_bounds__(256) void k_gated_norm(
    const short* __restrict__ ybuf, const short* __restrict__ zbf,
    const float* __restrict__ gw, short* __restrict__ y2b) {
  __shared__ float sred[4];
  const int row = blockIdx.x, tid = threadIdx.x;
  const short4v* y4 = (const short4v*)(ybuf + (size_t)row * INTER);
  const short4v* z4 = (const short4v*)(zbf + (size_t)row * INTER);
  float g[16];
  float ss = 0.f;
  #pragma unroll
  for (int i = 0; i < 4; ++i) {
    short4v y = y4[tid + i * 256];
    short4v z = z4[tid + i * 256];
    float g0 = bf2f(y.x) * siluf(bf2f(z.x)), g1 = bf2f(y.y) * siluf(bf2f(z.y));
    float g2 = bf2f(y.z) * siluf(bf2f(z.z)), g3 = bf2f(y.w) * siluf(bf2f(z.w));
    g[i*4+0] = g0; g[i*4+1] = g1; g[i*4+2] = g2; g[i*4+3] = g3;
    ss += g0*g0 + g1*g1 + g2*g2 + g3*g3;
  }
  #pragma unroll
  for (int off = 32; off >= 1; off >>= 1) ss += __shfl_down(ss, off);
  if ((tid & 63) == 0) sred[tid >> 6] = ss;
  __syncthreads();
  float tot = sred[0] + sred[1] + sred[2] + sred[3];
  float rs = rsqrtf(tot / (float)INTER + EPS);
  #pragma unroll
  for (int i = 0; i < 4; ++i) {
    int e = (tid + i * 256) * 4;
    short4v s;
    s.x = f2bf(g[i*4+0] * rs * gw[e+0]);
    s.y = f2bf(g[i*4+1] * rs * gw[e+1]);
    s.z = f2bf(g[i*4+2] * rs * gw[e+2]);
    s.w = f2bf(g[i*4+3] * rs * gw[e+3]);
    *(short4v*)(y2b + (size_t)row * INTER + e) = s;
  }
}

extern "C" void kernel_launch(void* const* d_in, const int* in_sizes, int n_in,
                              void* d_out, int out_size, void* d_ws, size_t ws_size,
                              hipStream_t stream) {
  const float* hid     = (const float*)d_in[0];
  const float* res     = (const float*)d_in[1];
  const float* norm_w  = (const float*)d_in[2];
  const float* w1      = (const float*)d_in[3];   // H x PROJ (K x N)
  const float* cw      = (const float*)d_in[4];   // CONV x 4
  const float* cb      = (const float*)d_in[5];
  const float* A_log   = (const float*)d_in[6];
  const float* dt_bias = (const float*)d_in[7];
  const float* Dp      = (const float*)d_in[8];
  const float* gw      = (const float*)d_in[9];
  const float* w2      = (const float*)d_in[10];  // INTER x H (K x N)

  float* out = (float*)d_out;
  float* resid_out = out + (size_t)LSEQ * HDIM;

  char* ws = (char*)d_ws;
  short* hsb  = (short*)(ws);                    // 512x2048 bf16   (2 MB)
  // [2097152, 38010880): 35.9 MB window, SEQUENTIAL lifetimes:
  //   1) hend/hinbuf/Pbuf/cdbuf — ssd/combine
  //   2) p2 (4x512x2048 bf16, 8.4MB) — gemm2 partials (after combine/fixup)
  float* hend   = (float*)(ws + 2097152);        // 8 MB
  short* p2     = (short*)(ws + 2097152);        // 8.4 MB (bf16 partials)
  float* hinbuf = (float*)(ws + 10485760);       // 8 MB
  float* Pbuf   = (float*)(ws + 18874368);
  float* cdbuf  = (float*)(ws + 18876416);       // 64x512 f32, head-major
  short* zbf  = (short*)(ws + 38010880);         // 512x4096 bf16   (4.2 MB)
  short* xbc  = (short*)(ws + 42205184);         // 512x4608 bf16   (4.7 MB)
  float* dtf  = (float*)(ws + 46923776);         // 512x64 f32
  short* convo= (short*)(ws + 55967744);         // 512x4608 bf16   (4.7 MB)
  float* dtb  = (float*)(ws + 65404928);         // 64x512 f32, head-major
  float* ldab = (float*)(ws + 65536000);         // 64x512 f32, head-major (log dA)
  short* ybuf = (short*)(ws + 65667072);         // 512x4096 bf16   (4.2 MB)
  short* y2b  = (short*)(ws + 74055680);         // 512x4096 bf16   (4.2 MB)
  short* w2t  = (short*)(ws + 78249984);         // 2048x4096 bf16  (16.8 MB)

  k_add_rmsnorm<<<LSEQ, 256, 0, stream>>>(hid, res, norm_w, resid_out, hsb);
  k_gemm1<<<(LSEQ/128)*(PROJC/64) + 512, 256, 0, stream>>>(hsb, w1, zbf, xbc, dtf, w2, w2t);
  k_conv<<<dim3(CONVC/256 + 1, NC), 256, 0, stream>>>(xbc, dtf, cw, cb, A_log, dt_bias, convo, dtb, ldab);
  k_ssd<<<dim3(NC, NH), 256, 0, stream>>>(convo, dtb, ldab, Dp, ybuf, hend, Pbuf, cdbuf);
  k_scan_combine<<<NHDN/256, 256, 0, stream>>>(hend, Pbuf, hinbuf);
  k_scan_fixup<<<(NC-1)*NH, 256, 0, stream>>>(convo, hinbuf, cdbuf, ybuf);
  k_gated_norm<<<LSEQ, 256, 0, stream>>>(ybuf, zbf, gw, y2b);
  k_gemm_bf16<64, 4><<<(LSEQ/64)*(HDIM/64)*4, 256, 0, stream>>>(y2b, w2t, p2, LSEQ, HDIM, INTER);
  k_reduce4<<<LSEQ*HDIM/1024, 256, 0, stream>>>(p2, out, LSEQ*HDIM);
}